// Round 1
// baseline (1034.689 us; speedup 1.0000x reference)
//
#include <hip/hip_runtime.h>
#include <cstdint>

// ResMLP + top2-MoE + final LN on MI355X.
// Pipeline:
//  1) transpose+convert weights: w1,w2 -> fp16 hi/lo planes [N,K]; ew1,ew2 -> fp16 [N,K]
//  2) ln1 -> h1 (fp16 hi/lo)
//  3) gemm_split: act = gelu(h1 @ w1 + b1)            (fp16-split x fp16-split, 3 MFMA)
//  4) gemm_split: h = act @ w2 + b2 + x  (fp32 out)
//  5) ln2: x2f = LN(h)+h (fp32, router-grade) ; x2h fp16 (expert input)
//  6) router (fp32 dots): top2, weights, counts
//  7) offsets (pad buckets to 128) + aux loss
//  8) scatter slots, gather rows -> xg
//  9) expert gemm1: a1 = gelu(xg @ ew1[e] + eb1[e])   (fp16 single)
// 10) expert gemm2: ybuf = a1 @ ew2[e] + eb2[e]  (fp32)
// 11) combine (w0*y0 + w1*y1) + final LN -> d_out ; aux at d_out[4096*2048... end]

#define NTOK 4096
#define HD 1024
#define MLPH 4096
#define EXPH 2048
#define NEXP 8
#define MAXSLOT 9216

typedef __attribute__((ext_vector_type(8))) _Float16 f16x8;
typedef __attribute__((ext_vector_type(4))) float f32x4v;

__device__ __forceinline__ float gelu_f(float v) {
  return 0.5f * v * (1.0f + erff(v * 0.7071067811865475f));
}

__device__ __forceinline__ void load16_lds(const void* g, void* lds) {
  __builtin_amdgcn_global_load_lds(
      (__attribute__((address_space(1))) unsigned int*)(uintptr_t)g,
      (__attribute__((address_space(3))) unsigned int*)(unsigned)(uintptr_t)lds,
      16, 0, 0);
}

// ---------------- transpose + convert ----------------
__global__ void transpose_split(const float* __restrict__ in,
                                _Float16* __restrict__ oh, _Float16* __restrict__ ol,
                                int R, int C) {
  __shared__ float t[32][33];
  size_t zo = (size_t)blockIdx.z * (size_t)R * (size_t)C;
  int c0 = blockIdx.x * 32, r0 = blockIdx.y * 32;
  int tx = threadIdx.x & 31, ty = threadIdx.x >> 5;
#pragma unroll
  for (int i = 0; i < 4; ++i)
    t[ty + i * 8][tx] = in[zo + (size_t)(r0 + ty + i * 8) * C + c0 + tx];
  __syncthreads();
#pragma unroll
  for (int i = 0; i < 4; ++i) {
    float v = t[tx][ty + i * 8];
    _Float16 h = (_Float16)v;
    size_t o = zo + (size_t)(c0 + ty + i * 8) * R + r0 + tx;
    oh[o] = h;
    ol[o] = (_Float16)((v - (float)h) * 2048.0f);
  }
}

__global__ void transpose_f16(const float* __restrict__ in, _Float16* __restrict__ out,
                              int R, int C) {
  __shared__ float t[32][33];
  size_t zo = (size_t)blockIdx.z * (size_t)R * (size_t)C;
  int c0 = blockIdx.x * 32, r0 = blockIdx.y * 32;
  int tx = threadIdx.x & 31, ty = threadIdx.x >> 5;
#pragma unroll
  for (int i = 0; i < 4; ++i)
    t[ty + i * 8][tx] = in[zo + (size_t)(r0 + ty + i * 8) * C + c0 + tx];
  __syncthreads();
#pragma unroll
  for (int i = 0; i < 4; ++i)
    out[zo + (size_t)(c0 + ty + i * 8) * R + r0 + tx] = (_Float16)t[tx][ty + i * 8];
}

// ---------------- LayerNorms ----------------
__global__ void ln1_kernel(const float* __restrict__ x, const float* __restrict__ g,
                           const float* __restrict__ b,
                           _Float16* __restrict__ oh, _Float16* __restrict__ ol) {
  int row = blockIdx.x, tid = threadIdx.x;
  const float4* xr = (const float4*)(x + (size_t)row * HD);
  float4 v = xr[tid];
  float s = v.x + v.y + v.z + v.w;
  float s2 = v.x * v.x + v.y * v.y + v.z * v.z + v.w * v.w;
  __shared__ float red[8];
#pragma unroll
  for (int o = 32; o > 0; o >>= 1) { s += __shfl_xor(s, o, 64); s2 += __shfl_xor(s2, o, 64); }
  if ((tid & 63) == 0) { red[tid >> 6] = s; red[(tid >> 6) + 4] = s2; }
  __syncthreads();
  s = red[0] + red[1] + red[2] + red[3];
  s2 = red[4] + red[5] + red[6] + red[7];
  float mu = s * (1.0f / HD);
  float rstd = 1.0f / sqrtf(s2 * (1.0f / HD) - mu * mu + 1e-5f);
  float4 gv = ((const float4*)g)[tid], bv = ((const float4*)b)[tid];
  float y[4];
  y[0] = (v.x - mu) * rstd * gv.x + bv.x;
  y[1] = (v.y - mu) * rstd * gv.y + bv.y;
  y[2] = (v.z - mu) * rstd * gv.z + bv.z;
  y[3] = (v.w - mu) * rstd * gv.w + bv.w;
  size_t base = (size_t)row * HD + tid * 4;
#pragma unroll
  for (int j = 0; j < 4; ++j) {
    _Float16 h = (_Float16)y[j];
    oh[base + j] = h;
    ol[base + j] = (_Float16)((y[j] - (float)h) * 2048.0f);
  }
}

__global__ void ln2_kernel(const float* __restrict__ hbuf, const float* __restrict__ g,
                           const float* __restrict__ b,
                           float* __restrict__ x2f, _Float16* __restrict__ x2h) {
  int row = blockIdx.x, tid = threadIdx.x;
  const float4* xr = (const float4*)(hbuf + (size_t)row * HD);
  float4 v = xr[tid];
  float s = v.x + v.y + v.z + v.w;
  float s2 = v.x * v.x + v.y * v.y + v.z * v.z + v.w * v.w;
  __shared__ float red[8];
#pragma unroll
  for (int o = 32; o > 0; o >>= 1) { s += __shfl_xor(s, o, 64); s2 += __shfl_xor(s2, o, 64); }
  if ((tid & 63) == 0) { red[tid >> 6] = s; red[(tid >> 6) + 4] = s2; }
  __syncthreads();
  s = red[0] + red[1] + red[2] + red[3];
  s2 = red[4] + red[5] + red[6] + red[7];
  float mu = s * (1.0f / HD);
  float rstd = 1.0f / sqrtf(s2 * (1.0f / HD) - mu * mu + 1e-5f);
  float4 gv = ((const float4*)g)[tid], bv = ((const float4*)b)[tid];
  float4 o4;
  o4.x = (v.x - mu) * rstd * gv.x + bv.x + v.x;
  o4.y = (v.y - mu) * rstd * gv.y + bv.y + v.y;
  o4.z = (v.z - mu) * rstd * gv.z + bv.z + v.z;
  o4.w = (v.w - mu) * rstd * gv.w + bv.w + v.w;
  ((float4*)(x2f + (size_t)row * HD))[tid] = o4;
  size_t base = (size_t)row * HD + tid * 4;
  x2h[base + 0] = (_Float16)o4.x;
  x2h[base + 1] = (_Float16)o4.y;
  x2h[base + 2] = (_Float16)o4.z;
  x2h[base + 3] = (_Float16)o4.w;
}

// ---------------- split-fp16 GEMM (resmlp), C = A @ Bt^T ----------------
// A,Bt both [rows, K] with K contiguous; hi/lo planes; acc = hh + (lh + hl)/2048
template <int EPI>  // 0: gelu -> fp16 hi/lo planes ; 1: +bias+res -> fp32
__global__ __launch_bounds__(256) void gemm_split(
    const _Float16* __restrict__ Ah, const _Float16* __restrict__ Al,
    const _Float16* __restrict__ Bh, const _Float16* __restrict__ Bl,
    const float* __restrict__ bias, const float* __restrict__ res,
    void* __restrict__ outA, void* __restrict__ outB, int N, int K) {
  int m0 = blockIdx.y * 128, n0 = blockIdx.x * 128;
  __shared__ __align__(16) _Float16 sAh[128 * 32], sAl[128 * 32];
  __shared__ __align__(16) _Float16 sBh[128 * 32], sBl[128 * 32];
  int tid = threadIdx.x, wave = tid >> 6, lane = tid & 63;
  int wm = wave >> 1, wn = wave & 1;
  f32x4v acc1[4][4] = {};
  f32x4v acc2[4][4] = {};
  const _Float16* pAh = Ah + (size_t)m0 * K;
  const _Float16* pAl = Al + (size_t)m0 * K;
  const _Float16* pBh = Bh + (size_t)n0 * K;
  const _Float16* pBl = Bl + (size_t)n0 * K;
  for (int k0 = 0; k0 < K; k0 += 32) {
    __syncthreads();
#pragma unroll
    for (int i = 0; i < 2; ++i) {
      int chunk = wave * 128 + i * 64 + lane;
      int row = chunk >> 2, c8 = (chunk & 3) * 8;
      size_t goff = (size_t)row * K + k0 + c8;
      int loff = (wave * 128 + i * 64) * 16;
      load16_lds(pAh + goff, (char*)sAh + loff);
      load16_lds(pAl + goff, (char*)sAl + loff);
      load16_lds(pBh + goff, (char*)sBh + loff);
      load16_lds(pBl + goff, (char*)sBl + loff);
    }
    __syncthreads();
    int r16 = lane & 15, q = lane >> 4;
    f16x8 ah[4], al[4], bh[4], bl[4];
#pragma unroll
    for (int t = 0; t < 4; ++t) {
      int ra = (wm * 64 + t * 16 + r16) * 32 + q * 8;
      int rb = (wn * 64 + t * 16 + r16) * 32 + q * 8;
      ah[t] = *(const f16x8*)&sAh[ra];
      al[t] = *(const f16x8*)&sAl[ra];
      bh[t] = *(const f16x8*)&sBh[rb];
      bl[t] = *(const f16x8*)&sBl[rb];
    }
#pragma unroll
    for (int mt = 0; mt < 4; ++mt)
#pragma unroll
      for (int nt = 0; nt < 4; ++nt) {
        acc1[mt][nt] = __builtin_amdgcn_mfma_f32_16x16x32_f16(ah[mt], bh[nt], acc1[mt][nt], 0, 0, 0);
        acc2[mt][nt] = __builtin_amdgcn_mfma_f32_16x16x32_f16(al[mt], bh[nt], acc2[mt][nt], 0, 0, 0);
        acc2[mt][nt] = __builtin_amdgcn_mfma_f32_16x16x32_f16(ah[mt], bl[nt], acc2[mt][nt], 0, 0, 0);
      }
  }
  int r16 = lane & 15, q = lane >> 4;
#pragma unroll
  for (int mt = 0; mt < 4; ++mt)
#pragma unroll
    for (int nt = 0; nt < 4; ++nt) {
      int col = n0 + wn * 64 + nt * 16 + r16;
      float bv = bias[col];
#pragma unroll
      for (int r = 0; r < 4; ++r) {
        size_t grow = (size_t)(m0 + wm * 64 + mt * 16 + q * 4 + r);
        float v = acc1[mt][nt][r] + acc2[mt][nt][r] * (1.0f / 2048.0f) + bv;
        if (EPI == 0) {
          v = gelu_f(v);
          _Float16 h = (_Float16)v;
          ((_Float16*)outA)[grow * N + col] = h;
          ((_Float16*)outB)[grow * N + col] = (_Float16)((v - (float)h) * 2048.0f);
        } else {
          ((float*)outA)[grow * N + col] = v + res[grow * N + col];
        }
      }
    }
}

// ---------------- single-fp16 GEMM (experts, padded buckets) ----------------
template <int EPI>  // 0: gelu -> fp16 ; 1: +bias -> fp32
__global__ __launch_bounds__(256) void gemm_expert(
    const _Float16* __restrict__ A, const _Float16* __restrict__ B,
    const float* __restrict__ bias, void* __restrict__ out,
    int N, int K, const int* __restrict__ poff, size_t bstride, int bias_stride) {
  int e = blockIdx.z;
  int m0;
  {
    int lo = poff[e], hi = poff[e + 1];
    m0 = lo + blockIdx.y * 128;
    if (m0 >= hi) return;
  }
  const _Float16* Bt = B + (size_t)e * bstride;
  const float* bias_e = bias + (size_t)e * bias_stride;
  int n0 = blockIdx.x * 128;
  __shared__ __align__(16) _Float16 sA[128 * 32];
  __shared__ __align__(16) _Float16 sB[128 * 32];
  int tid = threadIdx.x, wave = tid >> 6, lane = tid & 63;
  int wm = wave >> 1, wn = wave & 1;
  f32x4v acc[4][4] = {};
  const _Float16* pA = A + (size_t)m0 * K;
  const _Float16* pB = Bt + (size_t)n0 * K;
  for (int k0 = 0; k0 < K; k0 += 32) {
    __syncthreads();
#pragma unroll
    for (int i = 0; i < 2; ++i) {
      int chunk = wave * 128 + i * 64 + lane;
      int row = chunk >> 2, c8 = (chunk & 3) * 8;
      size_t goff = (size_t)row * K + k0 + c8;
      int loff = (wave * 128 + i * 64) * 16;
      load16_lds(pA + goff, (char*)sA + loff);
      load16_lds(pB + goff, (char*)sB + loff);
    }
    __syncthreads();
    int r16 = lane & 15, q = lane >> 4;
    f16x8 af[4], bf[4];
#pragma unroll
    for (int t = 0; t < 4; ++t) {
      af[t] = *(const f16x8*)&sA[(wm * 64 + t * 16 + r16) * 32 + q * 8];
      bf[t] = *(const f16x8*)&sB[(wn * 64 + t * 16 + r16) * 32 + q * 8];
    }
#pragma unroll
    for (int mt = 0; mt < 4; ++mt)
#pragma unroll
      for (int nt = 0; nt < 4; ++nt)
        acc[mt][nt] = __builtin_amdgcn_mfma_f32_16x16x32_f16(af[mt], bf[nt], acc[mt][nt], 0, 0, 0);
  }
  int r16 = lane & 15, q = lane >> 4;
#pragma unroll
  for (int mt = 0; mt < 4; ++mt)
#pragma unroll
    for (int nt = 0; nt < 4; ++nt) {
      int col = n0 + wn * 64 + nt * 16 + r16;
      float bv = bias_e[col];
#pragma unroll
      for (int r = 0; r < 4; ++r) {
        size_t grow = (size_t)(m0 + wm * 64 + mt * 16 + q * 4 + r);
        float v = acc[mt][nt][r] + bv;
        if (EPI == 0)
          ((_Float16*)out)[grow * N + col] = (_Float16)gelu_f(v);
        else
          ((float*)out)[grow * N + col] = v;
      }
    }
}

// ---------------- router / dispatch / combine ----------------
__global__ void router_kernel(const float* __restrict__ x2, const float* __restrict__ rw,
                              int* __restrict__ tidx, float* __restrict__ twt,
                              int* __restrict__ counts) {
  int token = blockIdx.x * 4 + (threadIdx.x >> 6);
  int lane = threadIdx.x & 63;
  const float* xr = x2 + (size_t)token * HD;
  float acc[8] = {0, 0, 0, 0, 0, 0, 0, 0};
  for (int k = lane; k < HD; k += 64) {
    float xv = xr[k];
    const float4* r4 = (const float4*)(rw + k * 8);
    float4 r0 = r4[0], r1 = r4[1];
    acc[0] += xv * r0.x; acc[1] += xv * r0.y; acc[2] += xv * r0.z; acc[3] += xv * r0.w;
    acc[4] += xv * r1.x; acc[5] += xv * r1.y; acc[6] += xv * r1.z; acc[7] += xv * r1.w;
  }
#pragma unroll
  for (int o = 32; o > 0; o >>= 1)
#pragma unroll
    for (int e = 0; e < 8; ++e) acc[e] += __shfl_xor(acc[e], o, 64);
  if (lane == 0) {
    int e0 = 0; float m0v = acc[0];
#pragma unroll
    for (int e = 1; e < 8; ++e) if (acc[e] > m0v) { m0v = acc[e]; e0 = e; }
    int e1 = -1; float m1v = -3.4e38f;
#pragma unroll
    for (int e = 0; e < 8; ++e) if (e != e0 && acc[e] > m1v) { m1v = acc[e]; e1 = e; }
    float p0 = 1.0f / (1.0f + expf(m1v - m0v));
    tidx[2 * token] = e0; tidx[2 * token + 1] = e1;
    twt[2 * token] = p0; twt[2 * token + 1] = 1.0f - p0;
    atomicAdd(&counts[e0], 1);
    atomicAdd(&counts[e1], 1);
  }
}

__global__ void offsets_aux_kernel(const int* __restrict__ counts, int* __restrict__ poff,
                                   float* __restrict__ auxp) {
  if (threadIdx.x == 0) {
    int acc = 0; poff[0] = 0; float aux = 0.0f;
    for (int e = 0; e < NEXP; ++e) {
      int c = counts[e];
      float load = (float)c / (float)(NTOK * 2);
      aux += load * logf(load + 1e-9f);
      acc += ((c + 127) >> 7) << 7;
      poff[e + 1] = acc;
    }
    auxp[0] = 0.01f * aux;
  }
}

__global__ void scatter_kernel(const int* __restrict__ tidx, const int* __restrict__ poff,
                               int* __restrict__ cursors, int* __restrict__ slotmap) {
  int t = blockIdx.x * 256 + threadIdx.x;
#pragma unroll
  for (int k = 0; k < 2; ++k) {
    int e = tidx[2 * t + k];
    int slot = poff[e] + atomicAdd(&cursors[e], 1);
    slotmap[2 * t + k] = slot;
  }
}

__global__ void gather_kernel(const int* __restrict__ slotmap, const _Float16* __restrict__ x2h,
                              _Float16* __restrict__ xg) {
  int p = blockIdx.x;
  int slot = slotmap[p];
  int token = p >> 1;
  const uint4* src = (const uint4*)(x2h + (size_t)token * HD);
  uint4* dst = (uint4*)(xg + (size_t)slot * HD);
  dst[threadIdx.x] = src[threadIdx.x];  // 128 thr x 16B = 2048B = 1024 fp16
}

__global__ void combine_ln_kernel(const float* __restrict__ ybuf, const int* __restrict__ slotmap,
                                  const float* __restrict__ twt, const float* __restrict__ g,
                                  const float* __restrict__ b, float* __restrict__ out) {
  int t = blockIdx.x, tid = threadIdx.x;
  int s0 = slotmap[2 * t], s1 = slotmap[2 * t + 1];
  float w0 = twt[2 * t], w1 = twt[2 * t + 1];
  float4 a = ((const float4*)(ybuf + (size_t)s0 * HD))[tid];
  float4 c = ((const float4*)(ybuf + (size_t)s1 * HD))[tid];
  float4 v;
  v.x = w0 * a.x + w1 * c.x; v.y = w0 * a.y + w1 * c.y;
  v.z = w0 * a.z + w1 * c.z; v.w = w0 * a.w + w1 * c.w;
  float s = v.x + v.y + v.z + v.w;
  float s2 = v.x * v.x + v.y * v.y + v.z * v.z + v.w * v.w;
  __shared__ float red[8];
#pragma unroll
  for (int o = 32; o > 0; o >>= 1) { s += __shfl_xor(s, o, 64); s2 += __shfl_xor(s2, o, 64); }
  if ((tid & 63) == 0) { red[tid >> 6] = s; red[(tid >> 6) + 4] = s2; }
  __syncthreads();
  s = red[0] + red[1] + red[2] + red[3];
  s2 = red[4] + red[5] + red[6] + red[7];
  float mu = s * (1.0f / HD);
  float rstd = 1.0f / sqrtf(s2 * (1.0f / HD) - mu * mu + 1e-5f);
  float4 gv = ((const float4*)g)[tid], bv = ((const float4*)b)[tid];
  float4 o4;
  o4.x = (v.x - mu) * rstd * gv.x + bv.x;
  o4.y = (v.y - mu) * rstd * gv.y + bv.y;
  o4.z = (v.z - mu) * rstd * gv.z + bv.z;
  o4.w = (v.w - mu) * rstd * gv.w + bv.w;
  ((float4*)(out + (size_t)t * HD))[tid] = o4;
}

// ---------------- launch ----------------
extern "C" void kernel_launch(void* const* d_in, const int* in_sizes, int n_in,
                              void* d_out, int out_size, void* d_ws, size_t ws_size,
                              hipStream_t stream) {
  const float* x    = (const float*)d_in[0];
  const float* ln1g = (const float*)d_in[1];
  const float* ln1b = (const float*)d_in[2];
  const float* ln2g = (const float*)d_in[3];
  const float* ln2b = (const float*)d_in[4];
  const float* w1   = (const float*)d_in[5];
  const float* b1   = (const float*)d_in[6];
  const float* w2   = (const float*)d_in[7];
  const float* b2   = (const float*)d_in[8];
  const float* rw   = (const float*)d_in[9];
  const float* ew1  = (const float*)d_in[10];
  const float* eb1  = (const float*)d_in[11];
  const float* ew2  = (const float*)d_in[12];
  const float* eb2  = (const float*)d_in[13];
  const float* lnfg = (const float*)d_in[14];
  const float* lnfb = (const float*)d_in[15];

  char* ws = (char*)d_ws;
  // weights region
  _Float16* w1th = (_Float16*)(ws + 0);
  _Float16* w1tl = (_Float16*)(ws + 8388608);
  _Float16* w2th = (_Float16*)(ws + 16777216);
  _Float16* w2tl = (_Float16*)(ws + 25165824);
  _Float16* ew1t = (_Float16*)(ws + 33554432);   // 8 x [2048,1024]
  _Float16* ew2t = (_Float16*)(ws + 67108864);   // 8 x [1024,2048]
  const size_t offA = 100663296;                 // h1 planes | xg
  _Float16* h1h = (_Float16*)(ws + offA);
  _Float16* h1l = (_Float16*)(ws + offA + 8388608);
  _Float16* xg  = (_Float16*)(ws + offA);        // [MAXSLOT,1024]
  const size_t offB = 119537664;                 // act planes | a1
  _Float16* acth = (_Float16*)(ws + offB);
  _Float16* actl = (_Float16*)(ws + offB + 33554432);
  _Float16* a1   = (_Float16*)(ws + offB);       // [MAXSLOT,2048]
  const size_t offC = 186646528;                 // h,x2f,x2h | ybuf
  float*    hbuf = (float*)(ws + offC);
  float*    x2f  = (float*)(ws + offC + 16777216);
  _Float16* x2h  = (_Float16*)(ws + offC + 33554432);
  float*    ybuf = (float*)(ws + offC);          // [MAXSLOT,1024] f32
  const size_t offS = 228589568;
  int*   counts  = (int*)(ws + offS);
  int*   cursors = (int*)(ws + offS + 32);
  int*   poff    = (int*)(ws + offS + 64);
  int*   tidx    = (int*)(ws + offS + 1024);
  float* twt     = (float*)(ws + offS + 1024 + 32768);
  int*   slotmap = (int*)(ws + offS + 1024 + 65536);

  float* out  = (float*)d_out;
  float* auxp = out + (size_t)NTOK * HD;

  dim3 b256(256);
  hipMemsetAsync(ws + offS, 0, 1024, stream);

  // weight conversion/transposition
  transpose_split<<<dim3(MLPH / 32, HD / 32, 1), b256, 0, stream>>>(w1, w1th, w1tl, HD, MLPH);
  transpose_split<<<dim3(HD / 32, MLPH / 32, 1), b256, 0, stream>>>(w2, w2th, w2tl, MLPH, HD);
  transpose_f16<<<dim3(EXPH / 32, HD / 32, NEXP), b256, 0, stream>>>(ew1, ew1t, HD, EXPH);
  transpose_f16<<<dim3(HD / 32, EXPH / 32, NEXP), b256, 0, stream>>>(ew2, ew2t, EXPH, HD);

  // resmlp
  ln1_kernel<<<NTOK, b256, 0, stream>>>(x, ln1g, ln1b, h1h, h1l);
  gemm_split<0><<<dim3(MLPH / 128, NTOK / 128, 1), b256, 0, stream>>>(
      h1h, h1l, w1th, w1tl, b1, nullptr, acth, actl, MLPH, HD);
  gemm_split<1><<<dim3(HD / 128, NTOK / 128, 1), b256, 0, stream>>>(
      acth, actl, w2th, w2tl, b2, x, hbuf, nullptr, HD, MLPH);
  ln2_kernel<<<NTOK, b256, 0, stream>>>(hbuf, ln2g, ln2b, x2f, x2h);

  // routing
  router_kernel<<<NTOK / 4, b256, 0, stream>>>(x2f, rw, tidx, twt, counts);
  offsets_aux_kernel<<<1, 64, 0, stream>>>(counts, poff, auxp);
  scatter_kernel<<<NTOK / 256, b256, 0, stream>>>(tidx, poff, cursors, slotmap);
  gather_kernel<<<NTOK * 2, dim3(128), 0, stream>>>(slotmap, x2h, xg);

  // experts (padded buckets, early-exit grid)
  gemm_expert<0><<<dim3(EXPH / 128, NTOK / 128, NEXP), b256, 0, stream>>>(
      xg, ew1t, eb1, a1, EXPH, HD, poff, (size_t)EXPH * HD, EXPH);
  gemm_expert<1><<<dim3(HD / 128, NTOK / 128, NEXP), b256, 0, stream>>>(
      a1, ew2t, eb2, ybuf, HD, EXPH, poff, (size_t)HD * EXPH, HD);

  // combine + final LN
  combine_ln_kernel<<<NTOK, b256, 0, stream>>>(ybuf, slotmap, twt, lnfg, lnfb, out);
}

// Round 2
// 956.304 us; speedup vs baseline: 1.0820x; 1.0820x over previous
//
#include <hip/hip_runtime.h>
#include <cstdint>

// ResMLP + top2-MoE + final LN on MI355X.
// R1: split-K x4 for the M=4096,N=1024,K=4096 resmlp GEMM2 (was 256 blocks =
// 1 wave/SIMD, 11% occupancy, 251us). Partials fp32 -> fused reduce+bias+res+LN2.
// Workspace overlays by lifetime; expert transposes enqueued after GEMM2 so
// their buffers reuse the dead act region.

#define NTOK 4096
#define HD 1024
#define MLPH 4096
#define EXPH 2048
#define NEXP 8
#define KSPLIT 4
#define KCH 1024

typedef __attribute__((ext_vector_type(8))) _Float16 f16x8;
typedef __attribute__((ext_vector_type(4))) float f32x4v;

__device__ __forceinline__ float gelu_f(float v) {
  return 0.5f * v * (1.0f + erff(v * 0.7071067811865475f));
}

__device__ __forceinline__ void load16_lds(const void* g, void* lds) {
  __builtin_amdgcn_global_load_lds(
      (__attribute__((address_space(1))) unsigned int*)(uintptr_t)g,
      (__attribute__((address_space(3))) unsigned int*)(unsigned)(uintptr_t)lds,
      16, 0, 0);
}

// ---------------- transpose + convert ----------------
__global__ void transpose_split(const float* __restrict__ in,
                                _Float16* __restrict__ oh, _Float16* __restrict__ ol,
                                int R, int C) {
  __shared__ float t[32][33];
  size_t zo = (size_t)blockIdx.z * (size_t)R * (size_t)C;
  int c0 = blockIdx.x * 32, r0 = blockIdx.y * 32;
  int tx = threadIdx.x & 31, ty = threadIdx.x >> 5;
#pragma unroll
  for (int i = 0; i < 4; ++i)
    t[ty + i * 8][tx] = in[zo + (size_t)(r0 + ty + i * 8) * C + c0 + tx];
  __syncthreads();
#pragma unroll
  for (int i = 0; i < 4; ++i) {
    float v = t[tx][ty + i * 8];
    _Float16 h = (_Float16)v;
    size_t o = zo + (size_t)(c0 + ty + i * 8) * R + r0 + tx;
    oh[o] = h;
    ol[o] = (_Float16)((v - (float)h) * 2048.0f);
  }
}

__global__ void transpose_f16(const float* __restrict__ in, _Float16* __restrict__ out,
                              int R, int C) {
  __shared__ float t[32][33];
  size_t zo = (size_t)blockIdx.z * (size_t)R * (size_t)C;
  int c0 = blockIdx.x * 32, r0 = blockIdx.y * 32;
  int tx = threadIdx.x & 31, ty = threadIdx.x >> 5;
#pragma unroll
  for (int i = 0; i < 4; ++i)
    t[ty + i * 8][tx] = in[zo + (size_t)(r0 + ty + i * 8) * C + c0 + tx];
  __syncthreads();
#pragma unroll
  for (int i = 0; i < 4; ++i)
    out[zo + (size_t)(c0 + ty + i * 8) * R + r0 + tx] = (_Float16)t[tx][ty + i * 8];
}

// ---------------- LN1 ----------------
__global__ void ln1_kernel(const float* __restrict__ x, const float* __restrict__ g,
                           const float* __restrict__ b,
                           _Float16* __restrict__ oh, _Float16* __restrict__ ol) {
  int row = blockIdx.x, tid = threadIdx.x;
  const float4* xr = (const float4*)(x + (size_t)row * HD);
  float4 v = xr[tid];
  float s = v.x + v.y + v.z + v.w;
  float s2 = v.x * v.x + v.y * v.y + v.z * v.z + v.w * v.w;
  __shared__ float red[8];
#pragma unroll
  for (int o = 32; o > 0; o >>= 1) { s += __shfl_xor(s, o, 64); s2 += __shfl_xor(s2, o, 64); }
  if ((tid & 63) == 0) { red[tid >> 6] = s; red[(tid >> 6) + 4] = s2; }
  __syncthreads();
  s = red[0] + red[1] + red[2] + red[3];
  s2 = red[4] + red[5] + red[6] + red[7];
  float mu = s * (1.0f / HD);
  float rstd = 1.0f / sqrtf(s2 * (1.0f / HD) - mu * mu + 1e-5f);
  float4 gv = ((const float4*)g)[tid], bv = ((const float4*)b)[tid];
  float y[4];
  y[0] = (v.x - mu) * rstd * gv.x + bv.x;
  y[1] = (v.y - mu) * rstd * gv.y + bv.y;
  y[2] = (v.z - mu) * rstd * gv.z + bv.z;
  y[3] = (v.w - mu) * rstd * gv.w + bv.w;
  size_t base = (size_t)row * HD + tid * 4;
#pragma unroll
  for (int j = 0; j < 4; ++j) {
    _Float16 h = (_Float16)y[j];
    oh[base + j] = h;
    ol[base + j] = (_Float16)((y[j] - (float)h) * 2048.0f);
  }
}

// ---------------- split-fp16 GEMM, gelu epilogue (resmlp gemm1) ----------------
__global__ __launch_bounds__(256) void gemm_split_gelu(
    const _Float16* __restrict__ Ah, const _Float16* __restrict__ Al,
    const _Float16* __restrict__ Bh, const _Float16* __restrict__ Bl,
    const float* __restrict__ bias,
    _Float16* __restrict__ outh, _Float16* __restrict__ outl, int N, int K) {
  int m0 = blockIdx.y * 128, n0 = blockIdx.x * 128;
  __shared__ __align__(16) _Float16 sAh[128 * 32], sAl[128 * 32];
  __shared__ __align__(16) _Float16 sBh[128 * 32], sBl[128 * 32];
  int tid = threadIdx.x, wave = tid >> 6, lane = tid & 63;
  int wm = wave >> 1, wn = wave & 1;
  f32x4v acc1[4][4] = {};
  f32x4v acc2[4][4] = {};
  const _Float16* pAh = Ah + (size_t)m0 * K;
  const _Float16* pAl = Al + (size_t)m0 * K;
  const _Float16* pBh = Bh + (size_t)n0 * K;
  const _Float16* pBl = Bl + (size_t)n0 * K;
  for (int k0 = 0; k0 < K; k0 += 32) {
    __syncthreads();
#pragma unroll
    for (int i = 0; i < 2; ++i) {
      int chunk = wave * 128 + i * 64 + lane;
      int row = chunk >> 2, c8 = (chunk & 3) * 8;
      size_t goff = (size_t)row * K + k0 + c8;
      int loff = (wave * 128 + i * 64) * 16;
      load16_lds(pAh + goff, (char*)sAh + loff);
      load16_lds(pAl + goff, (char*)sAl + loff);
      load16_lds(pBh + goff, (char*)sBh + loff);
      load16_lds(pBl + goff, (char*)sBl + loff);
    }
    __syncthreads();
    int r16 = lane & 15, q = lane >> 4;
    f16x8 ah[4], al[4], bh[4], bl[4];
#pragma unroll
    for (int t = 0; t < 4; ++t) {
      int ra = (wm * 64 + t * 16 + r16) * 32 + q * 8;
      int rb = (wn * 64 + t * 16 + r16) * 32 + q * 8;
      ah[t] = *(const f16x8*)&sAh[ra];
      al[t] = *(const f16x8*)&sAl[ra];
      bh[t] = *(const f16x8*)&sBh[rb];
      bl[t] = *(const f16x8*)&sBl[rb];
    }
#pragma unroll
    for (int mt = 0; mt < 4; ++mt)
#pragma unroll
      for (int nt = 0; nt < 4; ++nt) {
        acc1[mt][nt] = __builtin_amdgcn_mfma_f32_16x16x32_f16(ah[mt], bh[nt], acc1[mt][nt], 0, 0, 0);
        acc2[mt][nt] = __builtin_amdgcn_mfma_f32_16x16x32_f16(al[mt], bh[nt], acc2[mt][nt], 0, 0, 0);
        acc2[mt][nt] = __builtin_amdgcn_mfma_f32_16x16x32_f16(ah[mt], bl[nt], acc2[mt][nt], 0, 0, 0);
      }
  }
  int r16 = lane & 15, q = lane >> 4;
#pragma unroll
  for (int mt = 0; mt < 4; ++mt)
#pragma unroll
    for (int nt = 0; nt < 4; ++nt) {
      int col = n0 + wn * 64 + nt * 16 + r16;
      float bv = bias[col];
#pragma unroll
      for (int r = 0; r < 4; ++r) {
        size_t grow = (size_t)(m0 + wm * 64 + mt * 16 + q * 4 + r);
        float v = acc1[mt][nt][r] + acc2[mt][nt][r] * (1.0f / 2048.0f) + bv;
        v = gelu_f(v);
        _Float16 h = (_Float16)v;
        outh[grow * N + col] = h;
        outl[grow * N + col] = (_Float16)((v - (float)h) * 2048.0f);
      }
    }
}

// ---------------- split-fp16 GEMM, split-K partial output (resmlp gemm2) ----------------
__global__ __launch_bounds__(256) void gemm_split_pk(
    const _Float16* __restrict__ Ah, const _Float16* __restrict__ Al,
    const _Float16* __restrict__ Bh, const _Float16* __restrict__ Bl,
    float* __restrict__ part, int N, int K) {
  int m0 = blockIdx.y * 128, n0 = blockIdx.x * 128;
  int kbase = blockIdx.z * KCH;
  __shared__ __align__(16) _Float16 sAh[128 * 32], sAl[128 * 32];
  __shared__ __align__(16) _Float16 sBh[128 * 32], sBl[128 * 32];
  int tid = threadIdx.x, wave = tid >> 6, lane = tid & 63;
  int wm = wave >> 1, wn = wave & 1;
  f32x4v acc1[4][4] = {};
  f32x4v acc2[4][4] = {};
  const _Float16* pAh = Ah + (size_t)m0 * K + kbase;
  const _Float16* pAl = Al + (size_t)m0 * K + kbase;
  const _Float16* pBh = Bh + (size_t)n0 * K + kbase;
  const _Float16* pBl = Bl + (size_t)n0 * K + kbase;
  for (int k0 = 0; k0 < KCH; k0 += 32) {
    __syncthreads();
#pragma unroll
    for (int i = 0; i < 2; ++i) {
      int chunk = wave * 128 + i * 64 + lane;
      int row = chunk >> 2, c8 = (chunk & 3) * 8;
      size_t goff = (size_t)row * K + k0 + c8;
      int loff = (wave * 128 + i * 64) * 16;
      load16_lds(pAh + goff, (char*)sAh + loff);
      load16_lds(pAl + goff, (char*)sAl + loff);
      load16_lds(pBh + goff, (char*)sBh + loff);
      load16_lds(pBl + goff, (char*)sBl + loff);
    }
    __syncthreads();
    int r16 = lane & 15, q = lane >> 4;
    f16x8 ah[4], al[4], bh[4], bl[4];
#pragma unroll
    for (int t = 0; t < 4; ++t) {
      int ra = (wm * 64 + t * 16 + r16) * 32 + q * 8;
      int rb = (wn * 64 + t * 16 + r16) * 32 + q * 8;
      ah[t] = *(const f16x8*)&sAh[ra];
      al[t] = *(const f16x8*)&sAl[ra];
      bh[t] = *(const f16x8*)&sBh[rb];
      bl[t] = *(const f16x8*)&sBl[rb];
    }
#pragma unroll
    for (int mt = 0; mt < 4; ++mt)
#pragma unroll
      for (int nt = 0; nt < 4; ++nt) {
        acc1[mt][nt] = __builtin_amdgcn_mfma_f32_16x16x32_f16(ah[mt], bh[nt], acc1[mt][nt], 0, 0, 0);
        acc2[mt][nt] = __builtin_amdgcn_mfma_f32_16x16x32_f16(al[mt], bh[nt], acc2[mt][nt], 0, 0, 0);
        acc2[mt][nt] = __builtin_amdgcn_mfma_f32_16x16x32_f16(ah[mt], bl[nt], acc2[mt][nt], 0, 0, 0);
      }
  }
  int r16 = lane & 15, q = lane >> 4;
  float* pz = part + (size_t)blockIdx.z * NTOK * HD;
#pragma unroll
  for (int mt = 0; mt < 4; ++mt)
#pragma unroll
    for (int nt = 0; nt < 4; ++nt) {
      int col = n0 + wn * 64 + nt * 16 + r16;
#pragma unroll
      for (int r = 0; r < 4; ++r) {
        size_t grow = (size_t)(m0 + wm * 64 + mt * 16 + q * 4 + r);
        pz[grow * N + col] = acc1[mt][nt][r] + acc2[mt][nt][r] * (1.0f / 2048.0f);
      }
    }
}

// ---------------- reduce partials + bias + residual + LN2 ----------------
__global__ void reduce_ln2_kernel(const float* __restrict__ part, const float* __restrict__ x,
                                  const float* __restrict__ b2,
                                  const float* __restrict__ g, const float* __restrict__ b,
                                  float* __restrict__ x2f, _Float16* __restrict__ x2h) {
  int row = blockIdx.x, tid = threadIdx.x;
  float4 v = {0, 0, 0, 0};
#pragma unroll
  for (int z = 0; z < KSPLIT; ++z) {
    float4 p = ((const float4*)(part + ((size_t)z * NTOK + row) * HD))[tid];
    v.x += p.x; v.y += p.y; v.z += p.z; v.w += p.w;
  }
  float4 bb = ((const float4*)b2)[tid];
  float4 xv = ((const float4*)(x + (size_t)row * HD))[tid];
  v.x += bb.x + xv.x; v.y += bb.y + xv.y; v.z += bb.z + xv.z; v.w += bb.w + xv.w;
  float s = v.x + v.y + v.z + v.w;
  float s2 = v.x * v.x + v.y * v.y + v.z * v.z + v.w * v.w;
  __shared__ float red[8];
#pragma unroll
  for (int o = 32; o > 0; o >>= 1) { s += __shfl_xor(s, o, 64); s2 += __shfl_xor(s2, o, 64); }
  if ((tid & 63) == 0) { red[tid >> 6] = s; red[(tid >> 6) + 4] = s2; }
  __syncthreads();
  s = red[0] + red[1] + red[2] + red[3];
  s2 = red[4] + red[5] + red[6] + red[7];
  float mu = s * (1.0f / HD);
  float rstd = 1.0f / sqrtf(s2 * (1.0f / HD) - mu * mu + 1e-5f);
  float4 gv = ((const float4*)g)[tid], bv = ((const float4*)b)[tid];
  float4 o4;
  o4.x = (v.x - mu) * rstd * gv.x + bv.x + v.x;
  o4.y = (v.y - mu) * rstd * gv.y + bv.y + v.y;
  o4.z = (v.z - mu) * rstd * gv.z + bv.z + v.z;
  o4.w = (v.w - mu) * rstd * gv.w + bv.w + v.w;
  ((float4*)(x2f + (size_t)row * HD))[tid] = o4;
  size_t base = (size_t)row * HD + tid * 4;
  x2h[base + 0] = (_Float16)o4.x;
  x2h[base + 1] = (_Float16)o4.y;
  x2h[base + 2] = (_Float16)o4.z;
  x2h[base + 3] = (_Float16)o4.w;
}

// ---------------- single-fp16 GEMM (experts, padded buckets) ----------------
template <int EPI>  // 0: gelu -> fp16 ; 1: +bias -> fp32
__global__ __launch_bounds__(256) void gemm_expert(
    const _Float16* __restrict__ A, const _Float16* __restrict__ B,
    const float* __restrict__ bias, void* __restrict__ out,
    int N, int K, const int* __restrict__ poff, size_t bstride, int bias_stride) {
  int e = blockIdx.z;
  int m0;
  {
    int lo = poff[e], hi = poff[e + 1];
    m0 = lo + blockIdx.y * 128;
    if (m0 >= hi) return;
  }
  const _Float16* Bt = B + (size_t)e * bstride;
  const float* bias_e = bias + (size_t)e * bias_stride;
  int n0 = blockIdx.x * 128;
  __shared__ __align__(16) _Float16 sA[128 * 32];
  __shared__ __align__(16) _Float16 sB[128 * 32];
  int tid = threadIdx.x, wave = tid >> 6, lane = tid & 63;
  int wm = wave >> 1, wn = wave & 1;
  f32x4v acc[4][4] = {};
  const _Float16* pA = A + (size_t)m0 * K;
  const _Float16* pB = Bt + (size_t)n0 * K;
  for (int k0 = 0; k0 < K; k0 += 32) {
    __syncthreads();
#pragma unroll
    for (int i = 0; i < 2; ++i) {
      int chunk = wave * 128 + i * 64 + lane;
      int row = chunk >> 2, c8 = (chunk & 3) * 8;
      size_t goff = (size_t)row * K + k0 + c8;
      int loff = (wave * 128 + i * 64) * 16;
      load16_lds(pA + goff, (char*)sA + loff);
      load16_lds(pB + goff, (char*)sB + loff);
    }
    __syncthreads();
    int r16 = lane & 15, q = lane >> 4;
    f16x8 af[4], bf[4];
#pragma unroll
    for (int t = 0; t < 4; ++t) {
      af[t] = *(const f16x8*)&sA[(wm * 64 + t * 16 + r16) * 32 + q * 8];
      bf[t] = *(const f16x8*)&sB[(wn * 64 + t * 16 + r16) * 32 + q * 8];
    }
#pragma unroll
    for (int mt = 0; mt < 4; ++mt)
#pragma unroll
      for (int nt = 0; nt < 4; ++nt)
        acc[mt][nt] = __builtin_amdgcn_mfma_f32_16x16x32_f16(af[mt], bf[nt], acc[mt][nt], 0, 0, 0);
  }
  int r16 = lane & 15, q = lane >> 4;
#pragma unroll
  for (int mt = 0; mt < 4; ++mt)
#pragma unroll
    for (int nt = 0; nt < 4; ++nt) {
      int col = n0 + wn * 64 + nt * 16 + r16;
      float bv = bias_e[col];
#pragma unroll
      for (int r = 0; r < 4; ++r) {
        size_t grow = (size_t)(m0 + wm * 64 + mt * 16 + q * 4 + r);
        float v = acc[mt][nt][r] + bv;
        if (EPI == 0)
          ((_Float16*)out)[grow * N + col] = (_Float16)gelu_f(v);
        else
          ((float*)out)[grow * N + col] = v;
      }
    }
}

// ---------------- router / dispatch / combine ----------------
__global__ void router_kernel(const float* __restrict__ x2, const float* __restrict__ rw,
                              int* __restrict__ tidx, float* __restrict__ twt,
                              int* __restrict__ counts) {
  int token = blockIdx.x * 4 + (threadIdx.x >> 6);
  int lane = threadIdx.x & 63;
  const float* xr = x2 + (size_t)token * HD;
  float acc[8] = {0, 0, 0, 0, 0, 0, 0, 0};
  for (int k = lane; k < HD; k += 64) {
    float xv = xr[k];
    const float4* r4 = (const float4*)(rw + k * 8);
    float4 r0 = r4[0], r1 = r4[1];
    acc[0] += xv * r0.x; acc[1] += xv * r0.y; acc[2] += xv * r0.z; acc[3] += xv * r0.w;
    acc[4] += xv * r1.x; acc[5] += xv * r1.y; acc[6] += xv * r1.z; acc[7] += xv * r1.w;
  }
#pragma unroll
  for (int o = 32; o > 0; o >>= 1)
#pragma unroll
    for (int e = 0; e < 8; ++e) acc[e] += __shfl_xor(acc[e], o, 64);
  if (lane == 0) {
    int e0 = 0; float m0v = acc[0];
#pragma unroll
    for (int e = 1; e < 8; ++e) if (acc[e] > m0v) { m0v = acc[e]; e0 = e; }
    int e1 = -1; float m1v = -3.4e38f;
#pragma unroll
    for (int e = 0; e < 8; ++e) if (e != e0 && acc[e] > m1v) { m1v = acc[e]; e1 = e; }
    float p0 = 1.0f / (1.0f + expf(m1v - m0v));
    tidx[2 * token] = e0; tidx[2 * token + 1] = e1;
    twt[2 * token] = p0; twt[2 * token + 1] = 1.0f - p0;
    atomicAdd(&counts[e0], 1);
    atomicAdd(&counts[e1], 1);
  }
}

__global__ void offsets_aux_kernel(const int* __restrict__ counts, int* __restrict__ poff,
                                   float* __restrict__ auxp) {
  if (threadIdx.x == 0) {
    int acc = 0; poff[0] = 0; float aux = 0.0f;
    for (int e = 0; e < NEXP; ++e) {
      int c = counts[e];
      float load = (float)c / (float)(NTOK * 2);
      aux += load * logf(load + 1e-9f);
      acc += ((c + 127) >> 7) << 7;
      poff[e + 1] = acc;
    }
    auxp[0] = 0.01f * aux;
  }
}

__global__ void scatter_kernel(const int* __restrict__ tidx, const int* __restrict__ poff,
                               int* __restrict__ cursors, int* __restrict__ slotmap) {
  int t = blockIdx.x * 256 + threadIdx.x;
#pragma unroll
  for (int k = 0; k < 2; ++k) {
    int e = tidx[2 * t + k];
    int slot = poff[e] + atomicAdd(&cursors[e], 1);
    slotmap[2 * t + k] = slot;
  }
}

__global__ void gather_kernel(const int* __restrict__ slotmap, const _Float16* __restrict__ x2h,
                              _Float16* __restrict__ xg) {
  int p = blockIdx.x;
  int slot = slotmap[p];
  int token = p >> 1;
  const uint4* src = (const uint4*)(x2h + (size_t)token * HD);
  uint4* dst = (uint4*)(xg + (size_t)slot * HD);
  dst[threadIdx.x] = src[threadIdx.x];
}

__global__ void combine_ln_kernel(const float* __restrict__ ybuf, const int* __restrict__ slotmap,
                                  const float* __restrict__ twt, const float* __restrict__ g,
                                  const float* __restrict__ b, float* __restrict__ out) {
  int t = blockIdx.x, tid = threadIdx.x;
  int s0 = slotmap[2 * t], s1 = slotmap[2 * t + 1];
  float w0 = twt[2 * t], w1 = twt[2 * t + 1];
  float4 a = ((const float4*)(ybuf + (size_t)s0 * HD))[tid];
  float4 c = ((const float4*)(ybuf + (size_t)s1 * HD))[tid];
  float4 v;
  v.x = w0 * a.x + w1 * c.x; v.y = w0 * a.y + w1 * c.y;
  v.z = w0 * a.z + w1 * c.z; v.w = w0 * a.w + w1 * c.w;
  float s = v.x + v.y + v.z + v.w;
  float s2 = v.x * v.x + v.y * v.y + v.z * v.z + v.w * v.w;
  __shared__ float red[8];
#pragma unroll
  for (int o = 32; o > 0; o >>= 1) { s += __shfl_xor(s, o, 64); s2 += __shfl_xor(s2, o, 64); }
  if ((tid & 63) == 0) { red[tid >> 6] = s; red[(tid >> 6) + 4] = s2; }
  __syncthreads();
  s = red[0] + red[1] + red[2] + red[3];
  s2 = red[4] + red[5] + red[6] + red[7];
  float mu = s * (1.0f / HD);
  float rstd = 1.0f / sqrtf(s2 * (1.0f / HD) - mu * mu + 1e-5f);
  float4 gv = ((const float4*)g)[tid], bv = ((const float4*)b)[tid];
  float4 o4;
  o4.x = (v.x - mu) * rstd * gv.x + bv.x;
  o4.y = (v.y - mu) * rstd * gv.y + bv.y;
  o4.z = (v.z - mu) * rstd * gv.z + bv.z;
  o4.w = (v.w - mu) * rstd * gv.w + bv.w;
  ((float4*)(out + (size_t)t * HD))[tid] = o4;
}

// ---------------- launch ----------------
extern "C" void kernel_launch(void* const* d_in, const int* in_sizes, int n_in,
                              void* d_out, int out_size, void* d_ws, size_t ws_size,
                              hipStream_t stream) {
  const float* x    = (const float*)d_in[0];
  const float* ln1g = (const float*)d_in[1];
  const float* ln1b = (const float*)d_in[2];
  const float* ln2g = (const float*)d_in[3];
  const float* ln2b = (const float*)d_in[4];
  const float* w1   = (const float*)d_in[5];
  const float* b1   = (const float*)d_in[6];
  const float* w2   = (const float*)d_in[7];
  const float* b2   = (const float*)d_in[8];
  const float* rw   = (const float*)d_in[9];
  const float* ew1  = (const float*)d_in[10];
  const float* eb1  = (const float*)d_in[11];
  const float* ew2  = (const float*)d_in[12];
  const float* eb2  = (const float*)d_in[13];
  const float* lnfg = (const float*)d_in[14];
  const float* lnfb = (const float*)d_in[15];

  char* ws = (char*)d_ws;
  // Lifetime-overlaid layout (peak ~205.6 MB):
  //  [0,33.5M)    acth [steps g1..g2]      -> ew2t [after g2 .. eg2]
  //  [33.5,67.1M) actl                     -> ew1t [after g2 .. eg1]
  //  [67.1,75.5M) w1th [T..g1]             -> x2h  [ln2 .. gather]
  //  [75.5,83.9M) w1tl [T..g1]
  //  [83.9,100.7M) w2th+w2tl [T..g2]       -> x2f  [ln2 .. router]
  //  [100.7,167.8M) h1h+h1l [ln1..g1] -> part 64MB [g2..reduce] -> xg [gather..eg1] -> ybuf [eg2..combine]
  //  [167.8,205.5M) a1 [eg1..eg2]
  //  [205.5M+) scalars
  _Float16* acth = (_Float16*)(ws + 0);
  _Float16* actl = (_Float16*)(ws + 33554432);
  _Float16* ew2t = (_Float16*)(ws + 0);
  _Float16* ew1t = (_Float16*)(ws + 33554432);
  _Float16* w1th = (_Float16*)(ws + 67108864);
  _Float16* w1tl = (_Float16*)(ws + 75497472);
  _Float16* x2h  = (_Float16*)(ws + 67108864);
  _Float16* w2th = (_Float16*)(ws + 83886080);
  _Float16* w2tl = (_Float16*)(ws + 92274688);
  float*    x2f  = (float*)(ws + 83886080);
  _Float16* h1h  = (_Float16*)(ws + 100663296);
  _Float16* h1l  = (_Float16*)(ws + 109051904);
  float*    part = (float*)(ws + 100663296);   // 4 x [4096,1024] f32 = 64 MB
  _Float16* xg   = (_Float16*)(ws + 100663296);
  float*    ybuf = (float*)(ws + 100663296);
  _Float16* a1   = (_Float16*)(ws + 167772160);
  const size_t offS = 205520896;
  int*   counts  = (int*)(ws + offS);
  int*   cursors = (int*)(ws + offS + 32);
  int*   poff    = (int*)(ws + offS + 64);
  int*   tidx    = (int*)(ws + offS + 1024);
  float* twt     = (float*)(ws + offS + 1024 + 32768);
  int*   slotmap = (int*)(ws + offS + 1024 + 65536);

  float* out  = (float*)d_out;
  float* auxp = out + (size_t)NTOK * HD;

  dim3 b256(256);
  hipMemsetAsync(ws + offS, 0, 1024, stream);

  // resmlp weight conversion (expert transposes deferred: their dst overlays act)
  transpose_split<<<dim3(MLPH / 32, HD / 32, 1), b256, 0, stream>>>(w1, w1th, w1tl, HD, MLPH);
  transpose_split<<<dim3(HD / 32, MLPH / 32, 1), b256, 0, stream>>>(w2, w2th, w2tl, MLPH, HD);

  // resmlp
  ln1_kernel<<<NTOK, b256, 0, stream>>>(x, ln1g, ln1b, h1h, h1l);
  gemm_split_gelu<<<dim3(MLPH / 128, NTOK / 128, 1), b256, 0, stream>>>(
      h1h, h1l, w1th, w1tl, b1, acth, actl, MLPH, HD);
  gemm_split_pk<<<dim3(HD / 128, NTOK / 128, KSPLIT), b256, 0, stream>>>(
      acth, actl, w2th, w2tl, part, HD, MLPH);
  reduce_ln2_kernel<<<NTOK, b256, 0, stream>>>(part, x, b2, ln2g, ln2b, x2f, x2h);

  // expert weight transposes (act region now dead)
  transpose_f16<<<dim3(EXPH / 32, HD / 32, NEXP), b256, 0, stream>>>(ew1, ew1t, HD, EXPH);
  transpose_f16<<<dim3(HD / 32, EXPH / 32, NEXP), b256, 0, stream>>>(ew2, ew2t, EXPH, HD);

  // routing
  router_kernel<<<NTOK / 4, b256, 0, stream>>>(x2f, rw, tidx, twt, counts);
  offsets_aux_kernel<<<1, 64, 0, stream>>>(counts, poff, auxp);
  scatter_kernel<<<NTOK / 256, b256, 0, stream>>>(tidx, poff, cursors, slotmap);
  gather_kernel<<<NTOK * 2, dim3(128), 0, stream>>>(slotmap, x2h, xg);

  // experts (padded buckets, early-exit grid)
  gemm_expert<0><<<dim3(EXPH / 128, NTOK / 128, NEXP), b256, 0, stream>>>(
      xg, ew1t, eb1, a1, EXPH, HD, poff, (size_t)EXPH * HD, EXPH);
  gemm_expert<1><<<dim3(HD / 128, NTOK / 128, NEXP), b256, 0, stream>>>(
      a1, ew2t, eb2, ybuf, HD, EXPH, poff, (size_t)HD * EXPH, HD);

  // combine + final LN
  combine_ln_kernel<<<NTOK, b256, 0, stream>>>(ybuf, slotmap, twt, lnfg, lnfb, out);
}

// Round 3
// 804.598 us; speedup vs baseline: 1.2860x; 1.1885x over previous
//
#include <hip/hip_runtime.h>
#include <cstdint>

// ResMLP + top2-MoE + final LN on MI355X.
// R2: register-pressure fix for the split-fp16 GEMMs. R1 counters showed
// OccupancyPercent=11.3% (1 block/CU): 140 VGPR + 128 AGPR acc > 256 unified
// regs/wave. Restructure: B-frags (32 regs) live across mt loop, A-frags (8)
// loaded per-mt; __launch_bounds__(256,2) to target 2 waves/SIMD.

#define NTOK 4096
#define HD 1024
#define MLPH 4096
#define EXPH 2048
#define NEXP 8
#define KSPLIT 4
#define KCH 1024

typedef __attribute__((ext_vector_type(8))) _Float16 f16x8;
typedef __attribute__((ext_vector_type(4))) float f32x4v;

__device__ __forceinline__ float gelu_f(float v) {
  return 0.5f * v * (1.0f + erff(v * 0.7071067811865475f));
}

__device__ __forceinline__ void load16_lds(const void* g, void* lds) {
  __builtin_amdgcn_global_load_lds(
      (__attribute__((address_space(1))) unsigned int*)(uintptr_t)g,
      (__attribute__((address_space(3))) unsigned int*)(unsigned)(uintptr_t)lds,
      16, 0, 0);
}

// ---------------- transpose + convert ----------------
__global__ void transpose_split(const float* __restrict__ in,
                                _Float16* __restrict__ oh, _Float16* __restrict__ ol,
                                int R, int C) {
  __shared__ float t[32][33];
  size_t zo = (size_t)blockIdx.z * (size_t)R * (size_t)C;
  int c0 = blockIdx.x * 32, r0 = blockIdx.y * 32;
  int tx = threadIdx.x & 31, ty = threadIdx.x >> 5;
#pragma unroll
  for (int i = 0; i < 4; ++i)
    t[ty + i * 8][tx] = in[zo + (size_t)(r0 + ty + i * 8) * C + c0 + tx];
  __syncthreads();
#pragma unroll
  for (int i = 0; i < 4; ++i) {
    float v = t[tx][ty + i * 8];
    _Float16 h = (_Float16)v;
    size_t o = zo + (size_t)(c0 + ty + i * 8) * R + r0 + tx;
    oh[o] = h;
    ol[o] = (_Float16)((v - (float)h) * 2048.0f);
  }
}

__global__ void transpose_f16(const float* __restrict__ in, _Float16* __restrict__ out,
                              int R, int C) {
  __shared__ float t[32][33];
  size_t zo = (size_t)blockIdx.z * (size_t)R * (size_t)C;
  int c0 = blockIdx.x * 32, r0 = blockIdx.y * 32;
  int tx = threadIdx.x & 31, ty = threadIdx.x >> 5;
#pragma unroll
  for (int i = 0; i < 4; ++i)
    t[ty + i * 8][tx] = in[zo + (size_t)(r0 + ty + i * 8) * C + c0 + tx];
  __syncthreads();
#pragma unroll
  for (int i = 0; i < 4; ++i)
    out[zo + (size_t)(c0 + ty + i * 8) * R + r0 + tx] = (_Float16)t[tx][ty + i * 8];
}

// ---------------- LN1 ----------------
__global__ void ln1_kernel(const float* __restrict__ x, const float* __restrict__ g,
                           const float* __restrict__ b,
                           _Float16* __restrict__ oh, _Float16* __restrict__ ol) {
  int row = blockIdx.x, tid = threadIdx.x;
  const float4* xr = (const float4*)(x + (size_t)row * HD);
  float4 v = xr[tid];
  float s = v.x + v.y + v.z + v.w;
  float s2 = v.x * v.x + v.y * v.y + v.z * v.z + v.w * v.w;
  __shared__ float red[8];
#pragma unroll
  for (int o = 32; o > 0; o >>= 1) { s += __shfl_xor(s, o, 64); s2 += __shfl_xor(s2, o, 64); }
  if ((tid & 63) == 0) { red[tid >> 6] = s; red[(tid >> 6) + 4] = s2; }
  __syncthreads();
  s = red[0] + red[1] + red[2] + red[3];
  s2 = red[4] + red[5] + red[6] + red[7];
  float mu = s * (1.0f / HD);
  float rstd = 1.0f / sqrtf(s2 * (1.0f / HD) - mu * mu + 1e-5f);
  float4 gv = ((const float4*)g)[tid], bv = ((const float4*)b)[tid];
  float y[4];
  y[0] = (v.x - mu) * rstd * gv.x + bv.x;
  y[1] = (v.y - mu) * rstd * gv.y + bv.y;
  y[2] = (v.z - mu) * rstd * gv.z + bv.z;
  y[3] = (v.w - mu) * rstd * gv.w + bv.w;
  size_t base = (size_t)row * HD + tid * 4;
#pragma unroll
  for (int j = 0; j < 4; ++j) {
    _Float16 h = (_Float16)y[j];
    oh[base + j] = h;
    ol[base + j] = (_Float16)((y[j] - (float)h) * 2048.0f);
  }
}

// ---------------- split-fp16 GEMM, gelu epilogue (resmlp gemm1) ----------------
__global__ __launch_bounds__(256, 2) void gemm_split_gelu(
    const _Float16* __restrict__ Ah, const _Float16* __restrict__ Al,
    const _Float16* __restrict__ Bh, const _Float16* __restrict__ Bl,
    const float* __restrict__ bias,
    _Float16* __restrict__ outh, _Float16* __restrict__ outl, int N, int K) {
  int m0 = blockIdx.y * 128, n0 = blockIdx.x * 128;
  __shared__ __align__(16) _Float16 sAh[128 * 32], sAl[128 * 32];
  __shared__ __align__(16) _Float16 sBh[128 * 32], sBl[128 * 32];
  int tid = threadIdx.x, wave = tid >> 6, lane = tid & 63;
  int wm = wave >> 1, wn = wave & 1;
  f32x4v acc1[4][4] = {};
  f32x4v acc2[4][4] = {};
  const _Float16* pAh = Ah + (size_t)m0 * K;
  const _Float16* pAl = Al + (size_t)m0 * K;
  const _Float16* pBh = Bh + (size_t)n0 * K;
  const _Float16* pBl = Bl + (size_t)n0 * K;
  int r16 = lane & 15, q = lane >> 4;
  for (int k0 = 0; k0 < K; k0 += 32) {
    __syncthreads();
#pragma unroll
    for (int i = 0; i < 2; ++i) {
      int chunk = wave * 128 + i * 64 + lane;
      int row = chunk >> 2, c8 = (chunk & 3) * 8;
      size_t goff = (size_t)row * K + k0 + c8;
      int loff = (wave * 128 + i * 64) * 16;
      load16_lds(pAh + goff, (char*)sAh + loff);
      load16_lds(pAl + goff, (char*)sAl + loff);
      load16_lds(pBh + goff, (char*)sBh + loff);
      load16_lds(pBl + goff, (char*)sBl + loff);
    }
    __syncthreads();
    // B fragments stay live across the mt loop (32 regs); A frags per-mt (8).
    f16x8 bh[4], bl[4];
#pragma unroll
    for (int t = 0; t < 4; ++t) {
      int rb = (wn * 64 + t * 16 + r16) * 32 + q * 8;
      bh[t] = *(const f16x8*)&sBh[rb];
      bl[t] = *(const f16x8*)&sBl[rb];
    }
#pragma unroll
    for (int mt = 0; mt < 4; ++mt) {
      int ra = (wm * 64 + mt * 16 + r16) * 32 + q * 8;
      f16x8 ah = *(const f16x8*)&sAh[ra];
      f16x8 al = *(const f16x8*)&sAl[ra];
#pragma unroll
      for (int nt = 0; nt < 4; ++nt) {
        acc1[mt][nt] = __builtin_amdgcn_mfma_f32_16x16x32_f16(ah, bh[nt], acc1[mt][nt], 0, 0, 0);
        acc2[mt][nt] = __builtin_amdgcn_mfma_f32_16x16x32_f16(al, bh[nt], acc2[mt][nt], 0, 0, 0);
      }
#pragma unroll
      for (int nt = 0; nt < 4; ++nt)
        acc2[mt][nt] = __builtin_amdgcn_mfma_f32_16x16x32_f16(ah, bl[nt], acc2[mt][nt], 0, 0, 0);
    }
  }
#pragma unroll
  for (int mt = 0; mt < 4; ++mt)
#pragma unroll
    for (int nt = 0; nt < 4; ++nt) {
      int col = n0 + wn * 64 + nt * 16 + r16;
      float bv = bias[col];
#pragma unroll
      for (int r = 0; r < 4; ++r) {
        size_t grow = (size_t)(m0 + wm * 64 + mt * 16 + q * 4 + r);
        float v = acc1[mt][nt][r] + acc2[mt][nt][r] * (1.0f / 2048.0f) + bv;
        v = gelu_f(v);
        _Float16 h = (_Float16)v;
        outh[grow * N + col] = h;
        outl[grow * N + col] = (_Float16)((v - (float)h) * 2048.0f);
      }
    }
}

// ---------------- split-fp16 GEMM, split-K partial output (resmlp gemm2) ----------------
__global__ __launch_bounds__(256, 2) void gemm_split_pk(
    const _Float16* __restrict__ Ah, const _Float16* __restrict__ Al,
    const _Float16* __restrict__ Bh, const _Float16* __restrict__ Bl,
    float* __restrict__ part, int N, int K) {
  int m0 = blockIdx.y * 128, n0 = blockIdx.x * 128;
  int kbase = blockIdx.z * KCH;
  __shared__ __align__(16) _Float16 sAh[128 * 32], sAl[128 * 32];
  __shared__ __align__(16) _Float16 sBh[128 * 32], sBl[128 * 32];
  int tid = threadIdx.x, wave = tid >> 6, lane = tid & 63;
  int wm = wave >> 1, wn = wave & 1;
  f32x4v acc1[4][4] = {};
  f32x4v acc2[4][4] = {};
  const _Float16* pAh = Ah + (size_t)m0 * K + kbase;
  const _Float16* pAl = Al + (size_t)m0 * K + kbase;
  const _Float16* pBh = Bh + (size_t)n0 * K + kbase;
  const _Float16* pBl = Bl + (size_t)n0 * K + kbase;
  int r16 = lane & 15, q = lane >> 4;
  for (int k0 = 0; k0 < KCH; k0 += 32) {
    __syncthreads();
#pragma unroll
    for (int i = 0; i < 2; ++i) {
      int chunk = wave * 128 + i * 64 + lane;
      int row = chunk >> 2, c8 = (chunk & 3) * 8;
      size_t goff = (size_t)row * K + k0 + c8;
      int loff = (wave * 128 + i * 64) * 16;
      load16_lds(pAh + goff, (char*)sAh + loff);
      load16_lds(pAl + goff, (char*)sAl + loff);
      load16_lds(pBh + goff, (char*)sBh + loff);
      load16_lds(pBl + goff, (char*)sBl + loff);
    }
    __syncthreads();
    f16x8 bh[4], bl[4];
#pragma unroll
    for (int t = 0; t < 4; ++t) {
      int rb = (wn * 64 + t * 16 + r16) * 32 + q * 8;
      bh[t] = *(const f16x8*)&sBh[rb];
      bl[t] = *(const f16x8*)&sBl[rb];
    }
#pragma unroll
    for (int mt = 0; mt < 4; ++mt) {
      int ra = (wm * 64 + mt * 16 + r16) * 32 + q * 8;
      f16x8 ah = *(const f16x8*)&sAh[ra];
      f16x8 al = *(const f16x8*)&sAl[ra];
#pragma unroll
      for (int nt = 0; nt < 4; ++nt) {
        acc1[mt][nt] = __builtin_amdgcn_mfma_f32_16x16x32_f16(ah, bh[nt], acc1[mt][nt], 0, 0, 0);
        acc2[mt][nt] = __builtin_amdgcn_mfma_f32_16x16x32_f16(al, bh[nt], acc2[mt][nt], 0, 0, 0);
      }
#pragma unroll
      for (int nt = 0; nt < 4; ++nt)
        acc2[mt][nt] = __builtin_amdgcn_mfma_f32_16x16x32_f16(ah, bl[nt], acc2[mt][nt], 0, 0, 0);
    }
  }
  float* pz = part + (size_t)blockIdx.z * NTOK * HD;
#pragma unroll
  for (int mt = 0; mt < 4; ++mt)
#pragma unroll
    for (int nt = 0; nt < 4; ++nt) {
      int col = n0 + wn * 64 + nt * 16 + r16;
#pragma unroll
      for (int r = 0; r < 4; ++r) {
        size_t grow = (size_t)(m0 + wm * 64 + mt * 16 + q * 4 + r);
        pz[grow * N + col] = acc1[mt][nt][r] + acc2[mt][nt][r] * (1.0f / 2048.0f);
      }
    }
}

// ---------------- reduce partials + bias + residual + LN2 ----------------
__global__ void reduce_ln2_kernel(const float* __restrict__ part, const float* __restrict__ x,
                                  const float* __restrict__ b2,
                                  const float* __restrict__ g, const float* __restrict__ b,
                                  float* __restrict__ x2f, _Float16* __restrict__ x2h) {
  int row = blockIdx.x, tid = threadIdx.x;
  float4 v = {0, 0, 0, 0};
#pragma unroll
  for (int z = 0; z < KSPLIT; ++z) {
    float4 p = ((const float4*)(part + ((size_t)z * NTOK + row) * HD))[tid];
    v.x += p.x; v.y += p.y; v.z += p.z; v.w += p.w;
  }
  float4 bb = ((const float4*)b2)[tid];
  float4 xv = ((const float4*)(x + (size_t)row * HD))[tid];
  v.x += bb.x + xv.x; v.y += bb.y + xv.y; v.z += bb.z + xv.z; v.w += bb.w + xv.w;
  float s = v.x + v.y + v.z + v.w;
  float s2 = v.x * v.x + v.y * v.y + v.z * v.z + v.w * v.w;
  __shared__ float red[8];
#pragma unroll
  for (int o = 32; o > 0; o >>= 1) { s += __shfl_xor(s, o, 64); s2 += __shfl_xor(s2, o, 64); }
  if ((tid & 63) == 0) { red[tid >> 6] = s; red[(tid >> 6) + 4] = s2; }
  __syncthreads();
  s = red[0] + red[1] + red[2] + red[3];
  s2 = red[4] + red[5] + red[6] + red[7];
  float mu = s * (1.0f / HD);
  float rstd = 1.0f / sqrtf(s2 * (1.0f / HD) - mu * mu + 1e-5f);
  float4 gv = ((const float4*)g)[tid], bv = ((const float4*)b)[tid];
  float4 o4;
  o4.x = (v.x - mu) * rstd * gv.x + bv.x + v.x;
  o4.y = (v.y - mu) * rstd * gv.y + bv.y + v.y;
  o4.z = (v.z - mu) * rstd * gv.z + bv.z + v.z;
  o4.w = (v.w - mu) * rstd * gv.w + bv.w + v.w;
  ((float4*)(x2f + (size_t)row * HD))[tid] = o4;
  size_t base = (size_t)row * HD + tid * 4;
  x2h[base + 0] = (_Float16)o4.x;
  x2h[base + 1] = (_Float16)o4.y;
  x2h[base + 2] = (_Float16)o4.z;
  x2h[base + 3] = (_Float16)o4.w;
}

// ---------------- single-fp16 GEMM (experts, padded buckets) ----------------
template <int EPI>  // 0: gelu -> fp16 ; 1: +bias -> fp32
__global__ __launch_bounds__(256, 2) void gemm_expert(
    const _Float16* __restrict__ A, const _Float16* __restrict__ B,
    const float* __restrict__ bias, void* __restrict__ out,
    int N, int K, const int* __restrict__ poff, size_t bstride, int bias_stride) {
  int e = blockIdx.z;
  int m0;
  {
    int lo = poff[e], hi = poff[e + 1];
    m0 = lo + blockIdx.y * 128;
    if (m0 >= hi) return;
  }
  const _Float16* Bt = B + (size_t)e * bstride;
  const float* bias_e = bias + (size_t)e * bias_stride;
  int n0 = blockIdx.x * 128;
  __shared__ __align__(16) _Float16 sA[128 * 32];
  __shared__ __align__(16) _Float16 sB[128 * 32];
  int tid = threadIdx.x, wave = tid >> 6, lane = tid & 63;
  int wm = wave >> 1, wn = wave & 1;
  f32x4v acc[4][4] = {};
  const _Float16* pA = A + (size_t)m0 * K;
  const _Float16* pB = Bt + (size_t)n0 * K;
  int r16 = lane & 15, q = lane >> 4;
  for (int k0 = 0; k0 < K; k0 += 32) {
    __syncthreads();
#pragma unroll
    for (int i = 0; i < 2; ++i) {
      int chunk = wave * 128 + i * 64 + lane;
      int row = chunk >> 2, c8 = (chunk & 3) * 8;
      size_t goff = (size_t)row * K + k0 + c8;
      int loff = (wave * 128 + i * 64) * 16;
      load16_lds(pA + goff, (char*)sA + loff);
      load16_lds(pB + goff, (char*)sB + loff);
    }
    __syncthreads();
    f16x8 bf[4];
#pragma unroll
    for (int t = 0; t < 4; ++t)
      bf[t] = *(const f16x8*)&sB[(wn * 64 + t * 16 + r16) * 32 + q * 8];
#pragma unroll
    for (int mt = 0; mt < 4; ++mt) {
      f16x8 af = *(const f16x8*)&sA[(wm * 64 + mt * 16 + r16) * 32 + q * 8];
#pragma unroll
      for (int nt = 0; nt < 4; ++nt)
        acc[mt][nt] = __builtin_amdgcn_mfma_f32_16x16x32_f16(af, bf[nt], acc[mt][nt], 0, 0, 0);
    }
  }
#pragma unroll
  for (int mt = 0; mt < 4; ++mt)
#pragma unroll
    for (int nt = 0; nt < 4; ++nt) {
      int col = n0 + wn * 64 + nt * 16 + r16;
      float bv = bias_e[col];
#pragma unroll
      for (int r = 0; r < 4; ++r) {
        size_t grow = (size_t)(m0 + wm * 64 + mt * 16 + q * 4 + r);
        float v = acc[mt][nt][r] + bv;
        if (EPI == 0)
          ((_Float16*)out)[grow * N + col] = (_Float16)gelu_f(v);
        else
          ((float*)out)[grow * N + col] = v;
      }
    }
}

// ---------------- router / dispatch / combine ----------------
__global__ void router_kernel(const float* __restrict__ x2, const float* __restrict__ rw,
                              int* __restrict__ tidx, float* __restrict__ twt,
                              int* __restrict__ counts) {
  int token = blockIdx.x * 4 + (threadIdx.x >> 6);
  int lane = threadIdx.x & 63;
  const float* xr = x2 + (size_t)token * HD;
  float acc[8] = {0, 0, 0, 0, 0, 0, 0, 0};
  for (int k = lane; k < HD; k += 64) {
    float xv = xr[k];
    const float4* r4 = (const float4*)(rw + k * 8);
    float4 r0 = r4[0], r1 = r4[1];
    acc[0] += xv * r0.x; acc[1] += xv * r0.y; acc[2] += xv * r0.z; acc[3] += xv * r0.w;
    acc[4] += xv * r1.x; acc[5] += xv * r1.y; acc[6] += xv * r1.z; acc[7] += xv * r1.w;
  }
#pragma unroll
  for (int o = 32; o > 0; o >>= 1)
#pragma unroll
    for (int e = 0; e < 8; ++e) acc[e] += __shfl_xor(acc[e], o, 64);
  if (lane == 0) {
    int e0 = 0; float m0v = acc[0];
#pragma unroll
    for (int e = 1; e < 8; ++e) if (acc[e] > m0v) { m0v = acc[e]; e0 = e; }
    int e1 = -1; float m1v = -3.4e38f;
#pragma unroll
    for (int e = 0; e < 8; ++e) if (e != e0 && acc[e] > m1v) { m1v = acc[e]; e1 = e; }
    float p0 = 1.0f / (1.0f + expf(m1v - m0v));
    tidx[2 * token] = e0; tidx[2 * token + 1] = e1;
    twt[2 * token] = p0; twt[2 * token + 1] = 1.0f - p0;
    atomicAdd(&counts[e0], 1);
    atomicAdd(&counts[e1], 1);
  }
}

__global__ void offsets_aux_kernel(const int* __restrict__ counts, int* __restrict__ poff,
                                   float* __restrict__ auxp) {
  if (threadIdx.x == 0) {
    int acc = 0; poff[0] = 0; float aux = 0.0f;
    for (int e = 0; e < NEXP; ++e) {
      int c = counts[e];
      float load = (float)c / (float)(NTOK * 2);
      aux += load * logf(load + 1e-9f);
      acc += ((c + 127) >> 7) << 7;
      poff[e + 1] = acc;
    }
    auxp[0] = 0.01f * aux;
  }
}

__global__ void scatter_kernel(const int* __restrict__ tidx, const int* __restrict__ poff,
                               int* __restrict__ cursors, int* __restrict__ slotmap) {
  int t = blockIdx.x * 256 + threadIdx.x;
#pragma unroll
  for (int k = 0; k < 2; ++k) {
    int e = tidx[2 * t + k];
    int slot = poff[e] + atomicAdd(&cursors[e], 1);
    slotmap[2 * t + k] = slot;
  }
}

__global__ void gather_kernel(const int* __restrict__ slotmap, const _Float16* __restrict__ x2h,
                              _Float16* __restrict__ xg) {
  int p = blockIdx.x;
  int slot = slotmap[p];
  int token = p >> 1;
  const uint4* src = (const uint4*)(x2h + (size_t)token * HD);
  uint4* dst = (uint4*)(xg + (size_t)slot * HD);
  dst[threadIdx.x] = src[threadIdx.x];
}

__global__ void combine_ln_kernel(const float* __restrict__ ybuf, const int* __restrict__ slotmap,
                                  const float* __restrict__ twt, const float* __restrict__ g,
                                  const float* __restrict__ b, float* __restrict__ out) {
  int t = blockIdx.x, tid = threadIdx.x;
  int s0 = slotmap[2 * t], s1 = slotmap[2 * t + 1];
  float w0 = twt[2 * t], w1 = twt[2 * t + 1];
  float4 a = ((const float4*)(ybuf + (size_t)s0 * HD))[tid];
  float4 c = ((const float4*)(ybuf + (size_t)s1 * HD))[tid];
  float4 v;
  v.x = w0 * a.x + w1 * c.x; v.y = w0 * a.y + w1 * c.y;
  v.z = w0 * a.z + w1 * c.z; v.w = w0 * a.w + w1 * c.w;
  float s = v.x + v.y + v.z + v.w;
  float s2 = v.x * v.x + v.y * v.y + v.z * v.z + v.w * v.w;
  __shared__ float red[8];
#pragma unroll
  for (int o = 32; o > 0; o >>= 1) { s += __shfl_xor(s, o, 64); s2 += __shfl_xor(s2, o, 64); }
  if ((tid & 63) == 0) { red[tid >> 6] = s; red[(tid >> 6) + 4] = s2; }
  __syncthreads();
  s = red[0] + red[1] + red[2] + red[3];
  s2 = red[4] + red[5] + red[6] + red[7];
  float mu = s * (1.0f / HD);
  float rstd = 1.0f / sqrtf(s2 * (1.0f / HD) - mu * mu + 1e-5f);
  float4 gv = ((const float4*)g)[tid], bv = ((const float4*)b)[tid];
  float4 o4;
  o4.x = (v.x - mu) * rstd * gv.x + bv.x;
  o4.y = (v.y - mu) * rstd * gv.y + bv.y;
  o4.z = (v.z - mu) * rstd * gv.z + bv.z;
  o4.w = (v.w - mu) * rstd * gv.w + bv.w;
  ((float4*)(out + (size_t)t * HD))[tid] = o4;
}

// ---------------- launch ----------------
extern "C" void kernel_launch(void* const* d_in, const int* in_sizes, int n_in,
                              void* d_out, int out_size, void* d_ws, size_t ws_size,
                              hipStream_t stream) {
  const float* x    = (const float*)d_in[0];
  const float* ln1g = (const float*)d_in[1];
  const float* ln1b = (const float*)d_in[2];
  const float* ln2g = (const float*)d_in[3];
  const float* ln2b = (const float*)d_in[4];
  const float* w1   = (const float*)d_in[5];
  const float* b1   = (const float*)d_in[6];
  const float* w2   = (const float*)d_in[7];
  const float* b2   = (const float*)d_in[8];
  const float* rw   = (const float*)d_in[9];
  const float* ew1  = (const float*)d_in[10];
  const float* eb1  = (const float*)d_in[11];
  const float* ew2  = (const float*)d_in[12];
  const float* eb2  = (const float*)d_in[13];
  const float* lnfg = (const float*)d_in[14];
  const float* lnfb = (const float*)d_in[15];

  char* ws = (char*)d_ws;
  _Float16* acth = (_Float16*)(ws + 0);
  _Float16* actl = (_Float16*)(ws + 33554432);
  _Float16* ew2t = (_Float16*)(ws + 0);
  _Float16* ew1t = (_Float16*)(ws + 33554432);
  _Float16* w1th = (_Float16*)(ws + 67108864);
  _Float16* w1tl = (_Float16*)(ws + 75497472);
  _Float16* x2h  = (_Float16*)(ws + 67108864);
  _Float16* w2th = (_Float16*)(ws + 83886080);
  _Float16* w2tl = (_Float16*)(ws + 92274688);
  float*    x2f  = (float*)(ws + 83886080);
  _Float16* h1h  = (_Float16*)(ws + 100663296);
  _Float16* h1l  = (_Float16*)(ws + 109051904);
  float*    part = (float*)(ws + 100663296);   // 4 x [4096,1024] f32 = 64 MB
  _Float16* xg   = (_Float16*)(ws + 100663296);
  float*    ybuf = (float*)(ws + 100663296);
  _Float16* a1   = (_Float16*)(ws + 167772160);
  const size_t offS = 205520896;
  int*   counts  = (int*)(ws + offS);
  int*   cursors = (int*)(ws + offS + 32);
  int*   poff    = (int*)(ws + offS + 64);
  int*   tidx    = (int*)(ws + offS + 1024);
  float* twt     = (float*)(ws + offS + 1024 + 32768);
  int*   slotmap = (int*)(ws + offS + 1024 + 65536);

  float* out  = (float*)d_out;
  float* auxp = out + (size_t)NTOK * HD;

  dim3 b256(256);
  hipMemsetAsync(ws + offS, 0, 1024, stream);

  // resmlp weight conversion (expert transposes deferred: their dst overlays act)
  transpose_split<<<dim3(MLPH / 32, HD / 32, 1), b256, 0, stream>>>(w1, w1th, w1tl, HD, MLPH);
  transpose_split<<<dim3(HD / 32, MLPH / 32, 1), b256, 0, stream>>>(w2, w2th, w2tl, MLPH, HD);

  // resmlp
  ln1_kernel<<<NTOK, b256, 0, stream>>>(x, ln1g, ln1b, h1h, h1l);
  gemm_split_gelu<<<dim3(MLPH / 128, NTOK / 128, 1), b256, 0, stream>>>(
      h1h, h1l, w1th, w1tl, b1, acth, actl, MLPH, HD);
  gemm_split_pk<<<dim3(HD / 128, NTOK / 128, KSPLIT), b256, 0, stream>>>(
      acth, actl, w2th, w2tl, part, HD, MLPH);
  reduce_ln2_kernel<<<NTOK, b256, 0, stream>>>(part, x, b2, ln2g, ln2b, x2f, x2h);

  // expert weight transposes (act region now dead)
  transpose_f16<<<dim3(EXPH / 32, HD / 32, NEXP), b256, 0, stream>>>(ew1, ew1t, HD, EXPH);
  transpose_f16<<<dim3(HD / 32, EXPH / 32, NEXP), b256, 0, stream>>>(ew2, ew2t, EXPH, HD);

  // routing
  router_kernel<<<NTOK / 4, b256, 0, stream>>>(x2f, rw, tidx, twt, counts);
  offsets_aux_kernel<<<1, 64, 0, stream>>>(counts, poff, auxp);
  scatter_kernel<<<NTOK / 256, b256, 0, stream>>>(tidx, poff, cursors, slotmap);
  gather_kernel<<<NTOK * 2, dim3(128), 0, stream>>>(slotmap, x2h, xg);

  // experts (padded buckets, early-exit grid)
  gemm_expert<0><<<dim3(EXPH / 128, NTOK / 128, NEXP), b256, 0, stream>>>(
      xg, ew1t, eb1, a1, EXPH, HD, poff, (size_t)EXPH * HD, EXPH);
  gemm_expert<1><<<dim3(HD / 128, NTOK / 128, NEXP), b256, 0, stream>>>(
      a1, ew2t, eb2, ybuf, HD, EXPH, poff, (size_t)HD * EXPH, HD);

  // combine + final LN
  combine_ln_kernel<<<NTOK, b256, 0, stream>>>(ybuf, slotmap, twt, lnfg, lnfb, out);
}

// Round 4
// 774.433 us; speedup vs baseline: 1.3361x; 1.0390x over previous
//
#include <hip/hip_runtime.h>
#include <cstdint>

// ResMLP + top2-MoE + final LN on MI355X.
// R3: (a) XCD-aware block swizzle in gemm_split_pk — R2 showed FETCH=420MB vs
// 80MB unique because all x-siblings (sharing an A-tile) land on different
// XCDs (XCD = L%8). Remap so each XCD owns 16 (y,z) groups, x fastest.
// (b) Router fused into reduce_ln2 (logits computed from in-register x2);
// x2f buffer and router dispatch removed.

#define NTOK 4096
#define HD 1024
#define MLPH 4096
#define EXPH 2048
#define NEXP 8
#define KSPLIT 4
#define KCH 1024

typedef __attribute__((ext_vector_type(8))) _Float16 f16x8;
typedef __attribute__((ext_vector_type(4))) float f32x4v;

__device__ __forceinline__ float gelu_f(float v) {
  return 0.5f * v * (1.0f + erff(v * 0.7071067811865475f));
}

__device__ __forceinline__ void load16_lds(const void* g, void* lds) {
  __builtin_amdgcn_global_load_lds(
      (__attribute__((address_space(1))) unsigned int*)(uintptr_t)g,
      (__attribute__((address_space(3))) unsigned int*)(unsigned)(uintptr_t)lds,
      16, 0, 0);
}

// ---------------- transpose + convert ----------------
__global__ void transpose_split(const float* __restrict__ in,
                                _Float16* __restrict__ oh, _Float16* __restrict__ ol,
                                int R, int C) {
  __shared__ float t[32][33];
  size_t zo = (size_t)blockIdx.z * (size_t)R * (size_t)C;
  int c0 = blockIdx.x * 32, r0 = blockIdx.y * 32;
  int tx = threadIdx.x & 31, ty = threadIdx.x >> 5;
#pragma unroll
  for (int i = 0; i < 4; ++i)
    t[ty + i * 8][tx] = in[zo + (size_t)(r0 + ty + i * 8) * C + c0 + tx];
  __syncthreads();
#pragma unroll
  for (int i = 0; i < 4; ++i) {
    float v = t[tx][ty + i * 8];
    _Float16 h = (_Float16)v;
    size_t o = zo + (size_t)(c0 + ty + i * 8) * R + r0 + tx;
    oh[o] = h;
    ol[o] = (_Float16)((v - (float)h) * 2048.0f);
  }
}

__global__ void transpose_f16(const float* __restrict__ in, _Float16* __restrict__ out,
                              int R, int C) {
  __shared__ float t[32][33];
  size_t zo = (size_t)blockIdx.z * (size_t)R * (size_t)C;
  int c0 = blockIdx.x * 32, r0 = blockIdx.y * 32;
  int tx = threadIdx.x & 31, ty = threadIdx.x >> 5;
#pragma unroll
  for (int i = 0; i < 4; ++i)
    t[ty + i * 8][tx] = in[zo + (size_t)(r0 + ty + i * 8) * C + c0 + tx];
  __syncthreads();
#pragma unroll
  for (int i = 0; i < 4; ++i)
    out[zo + (size_t)(c0 + ty + i * 8) * R + r0 + tx] = (_Float16)t[tx][ty + i * 8];
}

// ---------------- LN1 ----------------
__global__ void ln1_kernel(const float* __restrict__ x, const float* __restrict__ g,
                           const float* __restrict__ b,
                           _Float16* __restrict__ oh, _Float16* __restrict__ ol) {
  int row = blockIdx.x, tid = threadIdx.x;
  const float4* xr = (const float4*)(x + (size_t)row * HD);
  float4 v = xr[tid];
  float s = v.x + v.y + v.z + v.w;
  float s2 = v.x * v.x + v.y * v.y + v.z * v.z + v.w * v.w;
  __shared__ float red[8];
#pragma unroll
  for (int o = 32; o > 0; o >>= 1) { s += __shfl_xor(s, o, 64); s2 += __shfl_xor(s2, o, 64); }
  if ((tid & 63) == 0) { red[tid >> 6] = s; red[(tid >> 6) + 4] = s2; }
  __syncthreads();
  s = red[0] + red[1] + red[2] + red[3];
  s2 = red[4] + red[5] + red[6] + red[7];
  float mu = s * (1.0f / HD);
  float rstd = 1.0f / sqrtf(s2 * (1.0f / HD) - mu * mu + 1e-5f);
  float4 gv = ((const float4*)g)[tid], bv = ((const float4*)b)[tid];
  float y[4];
  y[0] = (v.x - mu) * rstd * gv.x + bv.x;
  y[1] = (v.y - mu) * rstd * gv.y + bv.y;
  y[2] = (v.z - mu) * rstd * gv.z + bv.z;
  y[3] = (v.w - mu) * rstd * gv.w + bv.w;
  size_t base = (size_t)row * HD + tid * 4;
#pragma unroll
  for (int j = 0; j < 4; ++j) {
    _Float16 h = (_Float16)y[j];
    oh[base + j] = h;
    ol[base + j] = (_Float16)((y[j] - (float)h) * 2048.0f);
  }
}

// ---------------- split-fp16 GEMM, gelu epilogue (resmlp gemm1) ----------------
__global__ __launch_bounds__(256, 2) void gemm_split_gelu(
    const _Float16* __restrict__ Ah, const _Float16* __restrict__ Al,
    const _Float16* __restrict__ Bh, const _Float16* __restrict__ Bl,
    const float* __restrict__ bias,
    _Float16* __restrict__ outh, _Float16* __restrict__ outl, int N, int K) {
  int m0 = blockIdx.y * 128, n0 = blockIdx.x * 128;
  __shared__ __align__(16) _Float16 sAh[128 * 32], sAl[128 * 32];
  __shared__ __align__(16) _Float16 sBh[128 * 32], sBl[128 * 32];
  int tid = threadIdx.x, wave = tid >> 6, lane = tid & 63;
  int wm = wave >> 1, wn = wave & 1;
  f32x4v acc1[4][4] = {};
  f32x4v acc2[4][4] = {};
  const _Float16* pAh = Ah + (size_t)m0 * K;
  const _Float16* pAl = Al + (size_t)m0 * K;
  const _Float16* pBh = Bh + (size_t)n0 * K;
  const _Float16* pBl = Bl + (size_t)n0 * K;
  int r16 = lane & 15, q = lane >> 4;
  for (int k0 = 0; k0 < K; k0 += 32) {
    __syncthreads();
#pragma unroll
    for (int i = 0; i < 2; ++i) {
      int chunk = wave * 128 + i * 64 + lane;
      int row = chunk >> 2, c8 = (chunk & 3) * 8;
      size_t goff = (size_t)row * K + k0 + c8;
      int loff = (wave * 128 + i * 64) * 16;
      load16_lds(pAh + goff, (char*)sAh + loff);
      load16_lds(pAl + goff, (char*)sAl + loff);
      load16_lds(pBh + goff, (char*)sBh + loff);
      load16_lds(pBl + goff, (char*)sBl + loff);
    }
    __syncthreads();
    f16x8 bh[4], bl[4];
#pragma unroll
    for (int t = 0; t < 4; ++t) {
      int rb = (wn * 64 + t * 16 + r16) * 32 + q * 8;
      bh[t] = *(const f16x8*)&sBh[rb];
      bl[t] = *(const f16x8*)&sBl[rb];
    }
#pragma unroll
    for (int mt = 0; mt < 4; ++mt) {
      int ra = (wm * 64 + mt * 16 + r16) * 32 + q * 8;
      f16x8 ah = *(const f16x8*)&sAh[ra];
      f16x8 al = *(const f16x8*)&sAl[ra];
#pragma unroll
      for (int nt = 0; nt < 4; ++nt) {
        acc1[mt][nt] = __builtin_amdgcn_mfma_f32_16x16x32_f16(ah, bh[nt], acc1[mt][nt], 0, 0, 0);
        acc2[mt][nt] = __builtin_amdgcn_mfma_f32_16x16x32_f16(al, bh[nt], acc2[mt][nt], 0, 0, 0);
      }
#pragma unroll
      for (int nt = 0; nt < 4; ++nt)
        acc2[mt][nt] = __builtin_amdgcn_mfma_f32_16x16x32_f16(ah, bl[nt], acc2[mt][nt], 0, 0, 0);
    }
  }
#pragma unroll
  for (int mt = 0; mt < 4; ++mt)
#pragma unroll
    for (int nt = 0; nt < 4; ++nt) {
      int col = n0 + wn * 64 + nt * 16 + r16;
      float bv = bias[col];
#pragma unroll
      for (int r = 0; r < 4; ++r) {
        size_t grow = (size_t)(m0 + wm * 64 + mt * 16 + q * 4 + r);
        float v = acc1[mt][nt][r] + acc2[mt][nt][r] * (1.0f / 2048.0f) + bv;
        v = gelu_f(v);
        _Float16 h = (_Float16)v;
        outh[grow * N + col] = h;
        outl[grow * N + col] = (_Float16)((v - (float)h) * 2048.0f);
      }
    }
}

// ---------------- split-fp16 GEMM, split-K partial output (resmlp gemm2) ----------------
// XCD-aware swizzle: hardware assigns block L to XCD L%8; remap so XCD g owns
// (y,z) groups [16g,16g+16) with x fastest -> A-tile reused 8x within one L2,
// B z-slice (4MB) resident per XCD.
__global__ __launch_bounds__(256, 2) void gemm_split_pk(
    const _Float16* __restrict__ Ah, const _Float16* __restrict__ Al,
    const _Float16* __restrict__ Bh, const _Float16* __restrict__ Bl,
    float* __restrict__ part, int N, int K) {
  int L = blockIdx.x + 8 * (blockIdx.y + 32 * blockIdx.z);
  int g8 = L & 7, j = L >> 3;
  int yz = g8 * 16 + (j >> 3);
  int bx = j & 7;
  int by = yz & 31;
  int bz = yz >> 5;
  int m0 = by * 128, n0 = bx * 128;
  int kbase = bz * KCH;
  __shared__ __align__(16) _Float16 sAh[128 * 32], sAl[128 * 32];
  __shared__ __align__(16) _Float16 sBh[128 * 32], sBl[128 * 32];
  int tid = threadIdx.x, wave = tid >> 6, lane = tid & 63;
  int wm = wave >> 1, wn = wave & 1;
  f32x4v acc1[4][4] = {};
  f32x4v acc2[4][4] = {};
  const _Float16* pAh = Ah + (size_t)m0 * K + kbase;
  const _Float16* pAl = Al + (size_t)m0 * K + kbase;
  const _Float16* pBh = Bh + (size_t)n0 * K + kbase;
  const _Float16* pBl = Bl + (size_t)n0 * K + kbase;
  int r16 = lane & 15, q = lane >> 4;
  for (int k0 = 0; k0 < KCH; k0 += 32) {
    __syncthreads();
#pragma unroll
    for (int i = 0; i < 2; ++i) {
      int chunk = wave * 128 + i * 64 + lane;
      int row = chunk >> 2, c8 = (chunk & 3) * 8;
      size_t goff = (size_t)row * K + k0 + c8;
      int loff = (wave * 128 + i * 64) * 16;
      load16_lds(pAh + goff, (char*)sAh + loff);
      load16_lds(pAl + goff, (char*)sAl + loff);
      load16_lds(pBh + goff, (char*)sBh + loff);
      load16_lds(pBl + goff, (char*)sBl + loff);
    }
    __syncthreads();
    f16x8 bh[4], bl[4];
#pragma unroll
    for (int t = 0; t < 4; ++t) {
      int rb = (wn * 64 + t * 16 + r16) * 32 + q * 8;
      bh[t] = *(const f16x8*)&sBh[rb];
      bl[t] = *(const f16x8*)&sBl[rb];
    }
#pragma unroll
    for (int mt = 0; mt < 4; ++mt) {
      int ra = (wm * 64 + mt * 16 + r16) * 32 + q * 8;
      f16x8 ah = *(const f16x8*)&sAh[ra];
      f16x8 al = *(const f16x8*)&sAl[ra];
#pragma unroll
      for (int nt = 0; nt < 4; ++nt) {
        acc1[mt][nt] = __builtin_amdgcn_mfma_f32_16x16x32_f16(ah, bh[nt], acc1[mt][nt], 0, 0, 0);
        acc2[mt][nt] = __builtin_amdgcn_mfma_f32_16x16x32_f16(al, bh[nt], acc2[mt][nt], 0, 0, 0);
      }
#pragma unroll
      for (int nt = 0; nt < 4; ++nt)
        acc2[mt][nt] = __builtin_amdgcn_mfma_f32_16x16x32_f16(ah, bl[nt], acc2[mt][nt], 0, 0, 0);
    }
  }
  float* pz = part + (size_t)bz * NTOK * HD;
#pragma unroll
  for (int mt = 0; mt < 4; ++mt)
#pragma unroll
    for (int nt = 0; nt < 4; ++nt) {
      int col = n0 + wn * 64 + nt * 16 + r16;
#pragma unroll
      for (int r = 0; r < 4; ++r) {
        size_t grow = (size_t)(m0 + wm * 64 + mt * 16 + q * 4 + r);
        pz[grow * N + col] = acc1[mt][nt][r] + acc2[mt][nt][r] * (1.0f / 2048.0f);
      }
    }
}

// ------- reduce partials + bias + residual + LN2 + router (fused) -------
__global__ void reduce_ln2_router_kernel(
    const float* __restrict__ part, const float* __restrict__ x,
    const float* __restrict__ b2, const float* __restrict__ g,
    const float* __restrict__ b, const float* __restrict__ rw,
    _Float16* __restrict__ x2h, int* __restrict__ tidx, float* __restrict__ twt,
    int* __restrict__ counts) {
  int row = blockIdx.x, tid = threadIdx.x;
  int lane = tid & 63, wid = tid >> 6;
  float4 v = {0, 0, 0, 0};
#pragma unroll
  for (int z = 0; z < KSPLIT; ++z) {
    float4 p = ((const float4*)(part + ((size_t)z * NTOK + row) * HD))[tid];
    v.x += p.x; v.y += p.y; v.z += p.z; v.w += p.w;
  }
  float4 bb = ((const float4*)b2)[tid];
  float4 xv = ((const float4*)(x + (size_t)row * HD))[tid];
  v.x += bb.x + xv.x; v.y += bb.y + xv.y; v.z += bb.z + xv.z; v.w += bb.w + xv.w;
  float s = v.x + v.y + v.z + v.w;
  float s2 = v.x * v.x + v.y * v.y + v.z * v.z + v.w * v.w;
  __shared__ float red[8];
  __shared__ float sred[4][8];
#pragma unroll
  for (int o = 32; o > 0; o >>= 1) { s += __shfl_xor(s, o, 64); s2 += __shfl_xor(s2, o, 64); }
  if (lane == 0) { red[wid] = s; red[wid + 4] = s2; }
  __syncthreads();
  s = red[0] + red[1] + red[2] + red[3];
  s2 = red[4] + red[5] + red[6] + red[7];
  float mu = s * (1.0f / HD);
  float rstd = 1.0f / sqrtf(s2 * (1.0f / HD) - mu * mu + 1e-5f);
  float4 gv = ((const float4*)g)[tid], bv = ((const float4*)b)[tid];
  float4 o4;
  o4.x = (v.x - mu) * rstd * gv.x + bv.x + v.x;
  o4.y = (v.y - mu) * rstd * gv.y + bv.y + v.y;
  o4.z = (v.z - mu) * rstd * gv.z + bv.z + v.z;
  o4.w = (v.w - mu) * rstd * gv.w + bv.w + v.w;
  size_t base = (size_t)row * HD + tid * 4;
  x2h[base + 0] = (_Float16)o4.x;
  x2h[base + 1] = (_Float16)o4.y;
  x2h[base + 2] = (_Float16)o4.z;
  x2h[base + 3] = (_Float16)o4.w;
  // router logits: rw is [H][E] row-major; thread covers channels 4t..4t+3
  float lg[8] = {0, 0, 0, 0, 0, 0, 0, 0};
  {
    const float4* rp = (const float4*)(rw + (size_t)tid * 32);
    float xc[4] = {o4.x, o4.y, o4.z, o4.w};
#pragma unroll
    for (int jj = 0; jj < 4; ++jj) {
      float4 r0 = rp[jj * 2], r1 = rp[jj * 2 + 1];
      lg[0] += xc[jj] * r0.x; lg[1] += xc[jj] * r0.y;
      lg[2] += xc[jj] * r0.z; lg[3] += xc[jj] * r0.w;
      lg[4] += xc[jj] * r1.x; lg[5] += xc[jj] * r1.y;
      lg[6] += xc[jj] * r1.z; lg[7] += xc[jj] * r1.w;
    }
  }
#pragma unroll
  for (int o = 32; o > 0; o >>= 1)
#pragma unroll
    for (int e = 0; e < 8; ++e) lg[e] += __shfl_xor(lg[e], o, 64);
  if (lane == 0)
#pragma unroll
    for (int e = 0; e < 8; ++e) sred[wid][e] = lg[e];
  __syncthreads();
  if (tid == 0) {
    float l8[8];
#pragma unroll
    for (int e = 0; e < 8; ++e)
      l8[e] = sred[0][e] + sred[1][e] + sred[2][e] + sred[3][e];
    int e0 = 0; float m0v = l8[0];
#pragma unroll
    for (int e = 1; e < 8; ++e) if (l8[e] > m0v) { m0v = l8[e]; e0 = e; }
    int e1 = -1; float m1v = -3.4e38f;
#pragma unroll
    for (int e = 0; e < 8; ++e) if (e != e0 && l8[e] > m1v) { m1v = l8[e]; e1 = e; }
    float p0 = 1.0f / (1.0f + expf(m1v - m0v));
    tidx[2 * row] = e0; tidx[2 * row + 1] = e1;
    twt[2 * row] = p0; twt[2 * row + 1] = 1.0f - p0;
    atomicAdd(&counts[e0], 1);
    atomicAdd(&counts[e1], 1);
  }
}

// ---------------- single-fp16 GEMM (experts, padded buckets) ----------------
template <int EPI>  // 0: gelu -> fp16 ; 1: +bias -> fp32
__global__ __launch_bounds__(256, 2) void gemm_expert(
    const _Float16* __restrict__ A, const _Float16* __restrict__ B,
    const float* __restrict__ bias, void* __restrict__ out,
    int N, int K, const int* __restrict__ poff, size_t bstride, int bias_stride) {
  int e = blockIdx.z;
  int m0;
  {
    int lo = poff[e], hi = poff[e + 1];
    m0 = lo + blockIdx.y * 128;
    if (m0 >= hi) return;
  }
  const _Float16* Bt = B + (size_t)e * bstride;
  const float* bias_e = bias + (size_t)e * bias_stride;
  int n0 = blockIdx.x * 128;
  __shared__ __align__(16) _Float16 sA[128 * 32];
  __shared__ __align__(16) _Float16 sB[128 * 32];
  int tid = threadIdx.x, wave = tid >> 6, lane = tid & 63;
  int wm = wave >> 1, wn = wave & 1;
  f32x4v acc[4][4] = {};
  const _Float16* pA = A + (size_t)m0 * K;
  const _Float16* pB = Bt + (size_t)n0 * K;
  int r16 = lane & 15, q = lane >> 4;
  for (int k0 = 0; k0 < K; k0 += 32) {
    __syncthreads();
#pragma unroll
    for (int i = 0; i < 2; ++i) {
      int chunk = wave * 128 + i * 64 + lane;
      int row = chunk >> 2, c8 = (chunk & 3) * 8;
      size_t goff = (size_t)row * K + k0 + c8;
      int loff = (wave * 128 + i * 64) * 16;
      load16_lds(pA + goff, (char*)sA + loff);
      load16_lds(pB + goff, (char*)sB + loff);
    }
    __syncthreads();
    f16x8 bf[4];
#pragma unroll
    for (int t = 0; t < 4; ++t)
      bf[t] = *(const f16x8*)&sB[(wn * 64 + t * 16 + r16) * 32 + q * 8];
#pragma unroll
    for (int mt = 0; mt < 4; ++mt) {
      f16x8 af = *(const f16x8*)&sA[(wm * 64 + mt * 16 + r16) * 32 + q * 8];
#pragma unroll
      for (int nt = 0; nt < 4; ++nt)
        acc[mt][nt] = __builtin_amdgcn_mfma_f32_16x16x32_f16(af, bf[nt], acc[mt][nt], 0, 0, 0);
    }
  }
#pragma unroll
  for (int mt = 0; mt < 4; ++mt)
#pragma unroll
    for (int nt = 0; nt < 4; ++nt) {
      int col = n0 + wn * 64 + nt * 16 + r16;
      float bv = bias_e[col];
#pragma unroll
      for (int r = 0; r < 4; ++r) {
        size_t grow = (size_t)(m0 + wm * 64 + mt * 16 + q * 4 + r);
        float v = acc[mt][nt][r] + bv;
        if (EPI == 0)
          ((_Float16*)out)[grow * N + col] = (_Float16)gelu_f(v);
        else
          ((float*)out)[grow * N + col] = v;
      }
    }
}

// ---------------- dispatch / combine ----------------
__global__ void offsets_aux_kernel(const int* __restrict__ counts, int* __restrict__ poff,
                                   float* __restrict__ auxp) {
  if (threadIdx.x == 0) {
    int acc = 0; poff[0] = 0; float aux = 0.0f;
    for (int e = 0; e < NEXP; ++e) {
      int c = counts[e];
      float load = (float)c / (float)(NTOK * 2);
      aux += load * logf(load + 1e-9f);
      acc += ((c + 127) >> 7) << 7;
      poff[e + 1] = acc;
    }
    auxp[0] = 0.01f * aux;
  }
}

__global__ void scatter_kernel(const int* __restrict__ tidx, const int* __restrict__ poff,
                               int* __restrict__ cursors, int* __restrict__ slotmap) {
  int t = blockIdx.x * 256 + threadIdx.x;
#pragma unroll
  for (int k = 0; k < 2; ++k) {
    int e = tidx[2 * t + k];
    int slot = poff[e] + atomicAdd(&cursors[e], 1);
    slotmap[2 * t + k] = slot;
  }
}

__global__ void gather_kernel(const int* __restrict__ slotmap, const _Float16* __restrict__ x2h,
                              _Float16* __restrict__ xg) {
  int p = blockIdx.x;
  int slot = slotmap[p];
  int token = p >> 1;
  const uint4* src = (const uint4*)(x2h + (size_t)token * HD);
  uint4* dst = (uint4*)(xg + (size_t)slot * HD);
  dst[threadIdx.x] = src[threadIdx.x];
}

__global__ void combine_ln_kernel(const float* __restrict__ ybuf, const int* __restrict__ slotmap,
                                  const float* __restrict__ twt, const float* __restrict__ g,
                                  const float* __restrict__ b, float* __restrict__ out) {
  int t = blockIdx.x, tid = threadIdx.x;
  int s0 = slotmap[2 * t], s1 = slotmap[2 * t + 1];
  float w0 = twt[2 * t], w1 = twt[2 * t + 1];
  float4 a = ((const float4*)(ybuf + (size_t)s0 * HD))[tid];
  float4 c = ((const float4*)(ybuf + (size_t)s1 * HD))[tid];
  float4 v;
  v.x = w0 * a.x + w1 * c.x; v.y = w0 * a.y + w1 * c.y;
  v.z = w0 * a.z + w1 * c.z; v.w = w0 * a.w + w1 * c.w;
  float s = v.x + v.y + v.z + v.w;
  float s2 = v.x * v.x + v.y * v.y + v.z * v.z + v.w * v.w;
  __shared__ float red[8];
#pragma unroll
  for (int o = 32; o > 0; o >>= 1) { s += __shfl_xor(s, o, 64); s2 += __shfl_xor(s2, o, 64); }
  if ((tid & 63) == 0) { red[tid >> 6] = s; red[(tid >> 6) + 4] = s2; }
  __syncthreads();
  s = red[0] + red[1] + red[2] + red[3];
  s2 = red[4] + red[5] + red[6] + red[7];
  float mu = s * (1.0f / HD);
  float rstd = 1.0f / sqrtf(s2 * (1.0f / HD) - mu * mu + 1e-5f);
  float4 gv = ((const float4*)g)[tid], bv = ((const float4*)b)[tid];
  float4 o4;
  o4.x = (v.x - mu) * rstd * gv.x + bv.x;
  o4.y = (v.y - mu) * rstd * gv.y + bv.y;
  o4.z = (v.z - mu) * rstd * gv.z + bv.z;
  o4.w = (v.w - mu) * rstd * gv.w + bv.w;
  ((float4*)(out + (size_t)t * HD))[tid] = o4;
}

// ---------------- launch ----------------
extern "C" void kernel_launch(void* const* d_in, const int* in_sizes, int n_in,
                              void* d_out, int out_size, void* d_ws, size_t ws_size,
                              hipStream_t stream) {
  const float* x    = (const float*)d_in[0];
  const float* ln1g = (const float*)d_in[1];
  const float* ln1b = (const float*)d_in[2];
  const float* ln2g = (const float*)d_in[3];
  const float* ln2b = (const float*)d_in[4];
  const float* w1   = (const float*)d_in[5];
  const float* b1   = (const float*)d_in[6];
  const float* w2   = (const float*)d_in[7];
  const float* b2   = (const float*)d_in[8];
  const float* rw   = (const float*)d_in[9];
  const float* ew1  = (const float*)d_in[10];
  const float* eb1  = (const float*)d_in[11];
  const float* ew2  = (const float*)d_in[12];
  const float* eb2  = (const float*)d_in[13];
  const float* lnfg = (const float*)d_in[14];
  const float* lnfb = (const float*)d_in[15];

  char* ws = (char*)d_ws;
  _Float16* acth = (_Float16*)(ws + 0);
  _Float16* actl = (_Float16*)(ws + 33554432);
  _Float16* ew2t = (_Float16*)(ws + 0);
  _Float16* ew1t = (_Float16*)(ws + 33554432);
  _Float16* w1th = (_Float16*)(ws + 67108864);
  _Float16* w1tl = (_Float16*)(ws + 75497472);
  _Float16* x2h  = (_Float16*)(ws + 67108864);
  _Float16* w2th = (_Float16*)(ws + 83886080);
  _Float16* w2tl = (_Float16*)(ws + 92274688);
  _Float16* h1h  = (_Float16*)(ws + 100663296);
  _Float16* h1l  = (_Float16*)(ws + 109051904);
  float*    part = (float*)(ws + 100663296);   // 4 x [4096,1024] f32 = 64 MB
  _Float16* xg   = (_Float16*)(ws + 100663296);
  float*    ybuf = (float*)(ws + 100663296);
  _Float16* a1   = (_Float16*)(ws + 167772160);
  const size_t offS = 205520896;
  int*   counts  = (int*)(ws + offS);
  int*   cursors = (int*)(ws + offS + 32);
  int*   poff    = (int*)(ws + offS + 64);
  int*   tidx    = (int*)(ws + offS + 1024);
  float* twt     = (float*)(ws + offS + 1024 + 32768);
  int*   slotmap = (int*)(ws + offS + 1024 + 65536);

  float* out  = (float*)d_out;
  float* auxp = out + (size_t)NTOK * HD;

  dim3 b256(256);
  hipMemsetAsync(ws + offS, 0, 1024, stream);

  // resmlp weight conversion (expert transposes deferred: their dst overlays act)
  transpose_split<<<dim3(MLPH / 32, HD / 32, 1), b256, 0, stream>>>(w1, w1th, w1tl, HD, MLPH);
  transpose_split<<<dim3(HD / 32, MLPH / 32, 1), b256, 0, stream>>>(w2, w2th, w2tl, MLPH, HD);

  // resmlp
  ln1_kernel<<<NTOK, b256, 0, stream>>>(x, ln1g, ln1b, h1h, h1l);
  gemm_split_gelu<<<dim3(MLPH / 128, NTOK / 128, 1), b256, 0, stream>>>(
      h1h, h1l, w1th, w1tl, b1, acth, actl, MLPH, HD);
  gemm_split_pk<<<dim3(HD / 128, NTOK / 128, KSPLIT), b256, 0, stream>>>(
      acth, actl, w2th, w2tl, part, HD, MLPH);
  reduce_ln2_router_kernel<<<NTOK, b256, 0, stream>>>(
      part, x, b2, ln2g, ln2b, rw, x2h, tidx, twt, counts);

  // expert weight transposes (act region now dead)
  transpose_f16<<<dim3(EXPH / 32, HD / 32, NEXP), b256, 0, stream>>>(ew1, ew1t, HD, EXPH);
  transpose_f16<<<dim3(HD / 32, EXPH / 32, NEXP), b256, 0, stream>>>(ew2, ew2t, EXPH, HD);

  // routing tail
  offsets_aux_kernel<<<1, 64, 0, stream>>>(counts, poff, auxp);
  scatter_kernel<<<NTOK / 256, b256, 0, stream>>>(tidx, poff, cursors, slotmap);
  gather_kernel<<<NTOK * 2, dim3(128), 0, stream>>>(slotmap, x2h, xg);

  // experts (padded buckets, early-exit grid)
  gemm_expert<0><<<dim3(EXPH / 128, NTOK / 128, NEXP), b256, 0, stream>>>(
      xg, ew1t, eb1, a1, EXPH, HD, poff, (size_t)EXPH * HD, EXPH);
  gemm_expert<1><<<dim3(HD / 128, NTOK / 128, NEXP), b256, 0, stream>>>(
      a1, ew2t, eb2, ybuf, HD, EXPH, poff, (size_t)HD * EXPH, HD);

  // combine + final LN
  combine_ln_kernel<<<NTOK, b256, 0, stream>>>(ybuf, slotmap, twt, lnfg, lnfb, out);
}

// Round 5
// 700.686 us; speedup vs baseline: 1.4767x; 1.1053x over previous
//
#include <hip/hip_runtime.h>
#include <cstdint>

// ResMLP + top2-MoE + final LN on MI355X.
// R4: (a) BK=64 in all MFMA GEMMs (half the barrier drains; LDS 64KB/block,
// still 2 blocks/CU). (b) Dispatch-count reduction 15->11: merged transpose
// kernels, offsets+scatter fused into one block (emits slot->token), gather
// eliminated — expert gemm1 stages A from x2h via per-lane indirect
// global_load_lds (row->token lookups hoisted out of the K-loop).

#define NTOK 4096
#define HD 1024
#define MLPH 4096
#define EXPH 2048
#define NEXP 8
#define KSPLIT 4
#define KCH 1024
#define MAXSLOT 9216

typedef __attribute__((ext_vector_type(8))) _Float16 f16x8;
typedef __attribute__((ext_vector_type(4))) float f32x4v;

__device__ __forceinline__ float gelu_f(float v) {
  return 0.5f * v * (1.0f + erff(v * 0.7071067811865475f));
}

__device__ __forceinline__ void load16_lds(const void* g, void* lds) {
  __builtin_amdgcn_global_load_lds(
      (__attribute__((address_space(1))) unsigned int*)(uintptr_t)g,
      (__attribute__((address_space(3))) unsigned int*)(unsigned)(uintptr_t)lds,
      16, 0, 0);
}

// ---------------- merged transpose+convert (w1 & w2) ----------------
__global__ void transpose_split2(const float* __restrict__ w1, const float* __restrict__ w2,
                                 _Float16* __restrict__ o1h, _Float16* __restrict__ o1l,
                                 _Float16* __restrict__ o2h, _Float16* __restrict__ o2l) {
  __shared__ float t[32][33];
  int z = blockIdx.z;
  const float* in = z ? w2 : w1;
  _Float16* oh = z ? o2h : o1h;
  _Float16* ol = z ? o2l : o1l;
  int R = z ? MLPH : HD, C = z ? HD : MLPH;
  int c0 = (z ? blockIdx.y : blockIdx.x) * 32;
  int r0 = (z ? blockIdx.x : blockIdx.y) * 32;
  int tx = threadIdx.x & 31, ty = threadIdx.x >> 5;
#pragma unroll
  for (int i = 0; i < 4; ++i)
    t[ty + i * 8][tx] = in[(size_t)(r0 + ty + i * 8) * C + c0 + tx];
  __syncthreads();
#pragma unroll
  for (int i = 0; i < 4; ++i) {
    float v = t[tx][ty + i * 8];
    _Float16 h = (_Float16)v;
    size_t o = (size_t)(c0 + ty + i * 8) * R + r0 + tx;
    oh[o] = h;
    ol[o] = (_Float16)((v - (float)h) * 2048.0f);
  }
}

// ---------------- merged expert-weight transpose ----------------
__global__ void transpose_f16_2(const float* __restrict__ ew1, const float* __restrict__ ew2,
                                _Float16* __restrict__ ew1t, _Float16* __restrict__ ew2t) {
  __shared__ float t[32][33];
  int z = blockIdx.z;
  const float* in;
  _Float16* out;
  int R, C, c0, r0;
  if (z < 8) {
    in = ew1 + (size_t)z * HD * EXPH; out = ew1t + (size_t)z * HD * EXPH;
    R = HD; C = EXPH; c0 = blockIdx.x * 32; r0 = blockIdx.y * 32;
  } else {
    int e = z - 8;
    in = ew2 + (size_t)e * EXPH * HD; out = ew2t + (size_t)e * EXPH * HD;
    R = EXPH; C = HD; c0 = blockIdx.y * 32; r0 = blockIdx.x * 32;
  }
  int tx = threadIdx.x & 31, ty = threadIdx.x >> 5;
#pragma unroll
  for (int i = 0; i < 4; ++i)
    t[ty + i * 8][tx] = in[(size_t)(r0 + ty + i * 8) * C + c0 + tx];
  __syncthreads();
#pragma unroll
  for (int i = 0; i < 4; ++i)
    out[(size_t)(c0 + ty + i * 8) * R + r0 + tx] = (_Float16)t[tx][ty + i * 8];
}

// ---------------- LN1 ----------------
__global__ void ln1_kernel(const float* __restrict__ x, const float* __restrict__ g,
                           const float* __restrict__ b,
                           _Float16* __restrict__ oh, _Float16* __restrict__ ol) {
  int row = blockIdx.x, tid = threadIdx.x;
  const float4* xr = (const float4*)(x + (size_t)row * HD);
  float4 v = xr[tid];
  float s = v.x + v.y + v.z + v.w;
  float s2 = v.x * v.x + v.y * v.y + v.z * v.z + v.w * v.w;
  __shared__ float red[8];
#pragma unroll
  for (int o = 32; o > 0; o >>= 1) { s += __shfl_xor(s, o, 64); s2 += __shfl_xor(s2, o, 64); }
  if ((tid & 63) == 0) { red[tid >> 6] = s; red[(tid >> 6) + 4] = s2; }
  __syncthreads();
  s = red[0] + red[1] + red[2] + red[3];
  s2 = red[4] + red[5] + red[6] + red[7];
  float mu = s * (1.0f / HD);
  float rstd = 1.0f / sqrtf(s2 * (1.0f / HD) - mu * mu + 1e-5f);
  float4 gv = ((const float4*)g)[tid], bv = ((const float4*)b)[tid];
  float y[4];
  y[0] = (v.x - mu) * rstd * gv.x + bv.x;
  y[1] = (v.y - mu) * rstd * gv.y + bv.y;
  y[2] = (v.z - mu) * rstd * gv.z + bv.z;
  y[3] = (v.w - mu) * rstd * gv.w + bv.w;
  size_t base = (size_t)row * HD + tid * 4;
#pragma unroll
  for (int j = 0; j < 4; ++j) {
    _Float16 h = (_Float16)y[j];
    oh[base + j] = h;
    ol[base + j] = (_Float16)((y[j] - (float)h) * 2048.0f);
  }
}

// ---------------- split-fp16 GEMM, gelu epilogue (resmlp gemm1), BK=64 -------
__global__ __launch_bounds__(256, 2) void gemm_split_gelu(
    const _Float16* __restrict__ Ah, const _Float16* __restrict__ Al,
    const _Float16* __restrict__ Bh, const _Float16* __restrict__ Bl,
    const float* __restrict__ bias,
    _Float16* __restrict__ outh, _Float16* __restrict__ outl, int N, int K) {
  int m0 = blockIdx.y * 128, n0 = blockIdx.x * 128;
  __shared__ __align__(16) _Float16 sAh[128 * 64], sAl[128 * 64];
  __shared__ __align__(16) _Float16 sBh[128 * 64], sBl[128 * 64];
  int tid = threadIdx.x, wave = tid >> 6, lane = tid & 63;
  int wm = wave >> 1, wn = wave & 1;
  f32x4v acc1[4][4] = {};
  f32x4v acc2[4][4] = {};
  const _Float16* pAh = Ah + (size_t)m0 * K;
  const _Float16* pAl = Al + (size_t)m0 * K;
  const _Float16* pBh = Bh + (size_t)n0 * K;
  const _Float16* pBl = Bl + (size_t)n0 * K;
  int r16 = lane & 15, q = lane >> 4;
  for (int k0 = 0; k0 < K; k0 += 64) {
    __syncthreads();
#pragma unroll
    for (int i = 0; i < 4; ++i) {
      int s = i * 256 + wave * 64 + lane;
      int row = s >> 3, c2 = s & 7;
      size_t goff = (size_t)row * K + k0 + c2 * 8;
      int loff = (i * 256 + wave * 64) * 16;
      load16_lds(pAh + goff, (char*)sAh + loff);
      load16_lds(pAl + goff, (char*)sAl + loff);
      load16_lds(pBh + goff, (char*)sBh + loff);
      load16_lds(pBl + goff, (char*)sBl + loff);
    }
    __syncthreads();
#pragma unroll
    for (int ks = 0; ks < 2; ++ks) {
      f16x8 bh[4], bl[4];
#pragma unroll
      for (int t = 0; t < 4; ++t) {
        int rb = (wn * 64 + t * 16 + r16) * 64 + ks * 32 + q * 8;
        bh[t] = *(const f16x8*)&sBh[rb];
        bl[t] = *(const f16x8*)&sBl[rb];
      }
#pragma unroll
      for (int mt = 0; mt < 4; ++mt) {
        int ra = (wm * 64 + mt * 16 + r16) * 64 + ks * 32 + q * 8;
        f16x8 ah = *(const f16x8*)&sAh[ra];
        f16x8 al = *(const f16x8*)&sAl[ra];
#pragma unroll
        for (int nt = 0; nt < 4; ++nt) {
          acc1[mt][nt] = __builtin_amdgcn_mfma_f32_16x16x32_f16(ah, bh[nt], acc1[mt][nt], 0, 0, 0);
          acc2[mt][nt] = __builtin_amdgcn_mfma_f32_16x16x32_f16(al, bh[nt], acc2[mt][nt], 0, 0, 0);
        }
#pragma unroll
        for (int nt = 0; nt < 4; ++nt)
          acc2[mt][nt] = __builtin_amdgcn_mfma_f32_16x16x32_f16(ah, bl[nt], acc2[mt][nt], 0, 0, 0);
      }
    }
  }
#pragma unroll
  for (int mt = 0; mt < 4; ++mt)
#pragma unroll
    for (int nt = 0; nt < 4; ++nt) {
      int col = n0 + wn * 64 + nt * 16 + r16;
      float bv = bias[col];
#pragma unroll
      for (int r = 0; r < 4; ++r) {
        size_t grow = (size_t)(m0 + wm * 64 + mt * 16 + q * 4 + r);
        float v = acc1[mt][nt][r] + acc2[mt][nt][r] * (1.0f / 2048.0f) + bv;
        v = gelu_f(v);
        _Float16 h = (_Float16)v;
        outh[grow * N + col] = h;
        outl[grow * N + col] = (_Float16)((v - (float)h) * 2048.0f);
      }
    }
}

// ------ split-fp16 GEMM, split-K partials (resmlp gemm2), BK=64, swizzled ----
__global__ __launch_bounds__(256, 2) void gemm_split_pk(
    const _Float16* __restrict__ Ah, const _Float16* __restrict__ Al,
    const _Float16* __restrict__ Bh, const _Float16* __restrict__ Bl,
    float* __restrict__ part, int N, int K) {
  int L = blockIdx.x + 8 * (blockIdx.y + 32 * blockIdx.z);
  int g8 = L & 7, j = L >> 3;
  int yz = g8 * 16 + (j >> 3);
  int bx = j & 7;
  int by = yz & 31;
  int bz = yz >> 5;
  int m0 = by * 128, n0 = bx * 128;
  int kbase = bz * KCH;
  __shared__ __align__(16) _Float16 sAh[128 * 64], sAl[128 * 64];
  __shared__ __align__(16) _Float16 sBh[128 * 64], sBl[128 * 64];
  int tid = threadIdx.x, wave = tid >> 6, lane = tid & 63;
  int wm = wave >> 1, wn = wave & 1;
  f32x4v acc1[4][4] = {};
  f32x4v acc2[4][4] = {};
  const _Float16* pAh = Ah + (size_t)m0 * K + kbase;
  const _Float16* pAl = Al + (size_t)m0 * K + kbase;
  const _Float16* pBh = Bh + (size_t)n0 * K + kbase;
  const _Float16* pBl = Bl + (size_t)n0 * K + kbase;
  int r16 = lane & 15, q = lane >> 4;
  for (int k0 = 0; k0 < KCH; k0 += 64) {
    __syncthreads();
#pragma unroll
    for (int i = 0; i < 4; ++i) {
      int s = i * 256 + wave * 64 + lane;
      int row = s >> 3, c2 = s & 7;
      size_t goff = (size_t)row * K + k0 + c2 * 8;
      int loff = (i * 256 + wave * 64) * 16;
      load16_lds(pAh + goff, (char*)sAh + loff);
      load16_lds(pAl + goff, (char*)sAl + loff);
      load16_lds(pBh + goff, (char*)sBh + loff);
      load16_lds(pBl + goff, (char*)sBl + loff);
    }
    __syncthreads();
#pragma unroll
    for (int ks = 0; ks < 2; ++ks) {
      f16x8 bh[4], bl[4];
#pragma unroll
      for (int t = 0; t < 4; ++t) {
        int rb = (wn * 64 + t * 16 + r16) * 64 + ks * 32 + q * 8;
        bh[t] = *(const f16x8*)&sBh[rb];
        bl[t] = *(const f16x8*)&sBl[rb];
      }
#pragma unroll
      for (int mt = 0; mt < 4; ++mt) {
        int ra = (wm * 64 + mt * 16 + r16) * 64 + ks * 32 + q * 8;
        f16x8 ah = *(const f16x8*)&sAh[ra];
        f16x8 al = *(const f16x8*)&sAl[ra];
#pragma unroll
        for (int nt = 0; nt < 4; ++nt) {
          acc1[mt][nt] = __builtin_amdgcn_mfma_f32_16x16x32_f16(ah, bh[nt], acc1[mt][nt], 0, 0, 0);
          acc2[mt][nt] = __builtin_amdgcn_mfma_f32_16x16x32_f16(al, bh[nt], acc2[mt][nt], 0, 0, 0);
        }
#pragma unroll
        for (int nt = 0; nt < 4; ++nt)
          acc2[mt][nt] = __builtin_amdgcn_mfma_f32_16x16x32_f16(ah, bl[nt], acc2[mt][nt], 0, 0, 0);
      }
    }
  }
  float* pz = part + (size_t)bz * NTOK * HD;
#pragma unroll
  for (int mt = 0; mt < 4; ++mt)
#pragma unroll
    for (int nt = 0; nt < 4; ++nt) {
      int col = n0 + wn * 64 + nt * 16 + r16;
#pragma unroll
      for (int r = 0; r < 4; ++r) {
        size_t grow = (size_t)(m0 + wm * 64 + mt * 16 + q * 4 + r);
        pz[grow * N + col] = acc1[mt][nt][r] + acc2[mt][nt][r] * (1.0f / 2048.0f);
      }
    }
}

// ------- reduce partials + bias + residual + LN2 + router (fused) -------
__global__ void reduce_ln2_router_kernel(
    const float* __restrict__ part, const float* __restrict__ x,
    const float* __restrict__ b2, const float* __restrict__ g,
    const float* __restrict__ b, const float* __restrict__ rw,
    _Float16* __restrict__ x2h, int* __restrict__ tidx, float* __restrict__ twt,
    int* __restrict__ counts) {
  int row = blockIdx.x, tid = threadIdx.x;
  int lane = tid & 63, wid = tid >> 6;
  float4 v = {0, 0, 0, 0};
#pragma unroll
  for (int z = 0; z < KSPLIT; ++z) {
    float4 p = ((const float4*)(part + ((size_t)z * NTOK + row) * HD))[tid];
    v.x += p.x; v.y += p.y; v.z += p.z; v.w += p.w;
  }
  float4 bb = ((const float4*)b2)[tid];
  float4 xv = ((const float4*)(x + (size_t)row * HD))[tid];
  v.x += bb.x + xv.x; v.y += bb.y + xv.y; v.z += bb.z + xv.z; v.w += bb.w + xv.w;
  float s = v.x + v.y + v.z + v.w;
  float s2 = v.x * v.x + v.y * v.y + v.z * v.z + v.w * v.w;
  __shared__ float red[8];
  __shared__ float sred[4][8];
#pragma unroll
  for (int o = 32; o > 0; o >>= 1) { s += __shfl_xor(s, o, 64); s2 += __shfl_xor(s2, o, 64); }
  if (lane == 0) { red[wid] = s; red[wid + 4] = s2; }
  __syncthreads();
  s = red[0] + red[1] + red[2] + red[3];
  s2 = red[4] + red[5] + red[6] + red[7];
  float mu = s * (1.0f / HD);
  float rstd = 1.0f / sqrtf(s2 * (1.0f / HD) - mu * mu + 1e-5f);
  float4 gv = ((const float4*)g)[tid], bv = ((const float4*)b)[tid];
  float4 o4;
  o4.x = (v.x - mu) * rstd * gv.x + bv.x + v.x;
  o4.y = (v.y - mu) * rstd * gv.y + bv.y + v.y;
  o4.z = (v.z - mu) * rstd * gv.z + bv.z + v.z;
  o4.w = (v.w - mu) * rstd * gv.w + bv.w + v.w;
  size_t base = (size_t)row * HD + tid * 4;
  x2h[base + 0] = (_Float16)o4.x;
  x2h[base + 1] = (_Float16)o4.y;
  x2h[base + 2] = (_Float16)o4.z;
  x2h[base + 3] = (_Float16)o4.w;
  float lg[8] = {0, 0, 0, 0, 0, 0, 0, 0};
  {
    const float4* rp = (const float4*)(rw + (size_t)tid * 32);
    float xc[4] = {o4.x, o4.y, o4.z, o4.w};
#pragma unroll
    for (int jj = 0; jj < 4; ++jj) {
      float4 r0 = rp[jj * 2], r1 = rp[jj * 2 + 1];
      lg[0] += xc[jj] * r0.x; lg[1] += xc[jj] * r0.y;
      lg[2] += xc[jj] * r0.z; lg[3] += xc[jj] * r0.w;
      lg[4] += xc[jj] * r1.x; lg[5] += xc[jj] * r1.y;
      lg[6] += xc[jj] * r1.z; lg[7] += xc[jj] * r1.w;
    }
  }
#pragma unroll
  for (int o = 32; o > 0; o >>= 1)
#pragma unroll
    for (int e = 0; e < 8; ++e) lg[e] += __shfl_xor(lg[e], o, 64);
  if (lane == 0)
#pragma unroll
    for (int e = 0; e < 8; ++e) sred[wid][e] = lg[e];
  __syncthreads();
  if (tid == 0) {
    float l8[8];
#pragma unroll
    for (int e = 0; e < 8; ++e)
      l8[e] = sred[0][e] + sred[1][e] + sred[2][e] + sred[3][e];
    int e0 = 0; float m0v = l8[0];
#pragma unroll
    for (int e = 1; e < 8; ++e) if (l8[e] > m0v) { m0v = l8[e]; e0 = e; }
    int e1 = -1; float m1v = -3.4e38f;
#pragma unroll
    for (int e = 0; e < 8; ++e) if (e != e0 && l8[e] > m1v) { m1v = l8[e]; e1 = e; }
    float p0 = 1.0f / (1.0f + expf(m1v - m0v));
    tidx[2 * row] = e0; tidx[2 * row + 1] = e1;
    twt[2 * row] = p0; twt[2 * row + 1] = 1.0f - p0;
    atomicAdd(&counts[e0], 1);
    atomicAdd(&counts[e1], 1);
  }
}

// ------- offsets + aux + scatter + slot->token (single block) -------
__global__ void route_block(const int* __restrict__ counts, const int* __restrict__ tidx,
                            int* __restrict__ poff_g, float* __restrict__ auxp,
                            int* __restrict__ slotmap, int* __restrict__ slot2token) {
  __shared__ int poff[9];
  __shared__ int cur[8];
  int tid = threadIdx.x;
  if (tid == 0) {
    int acc = 0; poff[0] = 0; float aux = 0.0f;
    for (int e = 0; e < NEXP; ++e) {
      int c = counts[e];
      float load = (float)c / (float)(NTOK * 2);
      aux += load * logf(load + 1e-9f);
      acc += ((c + 127) >> 7) << 7;
      poff[e + 1] = acc;
    }
    auxp[0] = 0.01f * aux;
  }
  if (tid < 8) cur[tid] = 0;
  __syncthreads();
  for (int t = tid; t < NTOK; t += 256) {
#pragma unroll
    for (int k = 0; k < 2; ++k) {
      int e = tidx[2 * t + k];
      int slot = poff[e] + atomicAdd(&cur[e], 1);
      slotmap[2 * t + k] = slot;
      slot2token[slot] = t;
    }
  }
  __syncthreads();
  // pad slots -> token 0 (compute discarded in combine)
  for (int e = 0; e < NEXP; ++e) {
    int lo = poff[e] + counts[e], hi = poff[e + 1];
    for (int s2 = lo + tid; s2 < hi; s2 += 256) slot2token[s2] = 0;
  }
  if (tid < 9) poff_g[tid] = poff[tid];
}

// ------- single-fp16 GEMM (experts, padded buckets), BK=64 -------
// EPI==0: A rows indirect via slot2token (x2h source), gelu -> fp16
// EPI==1: A rows direct (a1), +bias -> fp32
template <int EPI>
__global__ __launch_bounds__(256, 2) void gemm_expert(
    const _Float16* __restrict__ A, const _Float16* __restrict__ B,
    const float* __restrict__ bias, void* __restrict__ out,
    int N, int K, const int* __restrict__ poff, size_t bstride, int bias_stride,
    const int* __restrict__ s2t) {
  int e = blockIdx.z;
  int lo = poff[e], hi = poff[e + 1];
  int m0 = lo + blockIdx.y * 128;
  if (m0 >= hi) return;
  const _Float16* Bt = B + (size_t)e * bstride;
  const float* bias_e = bias + (size_t)e * bias_stride;
  int n0 = blockIdx.x * 128;
  __shared__ __align__(16) _Float16 sA[128 * 64];
  __shared__ __align__(16) _Float16 sB[128 * 64];
  int tid = threadIdx.x, wave = tid >> 6, lane = tid & 63;
  int wm = wave >> 1, wn = wave & 1;
  int r16 = lane & 15, q = lane >> 4;
  f32x4v acc[4][4] = {};
  // row sources are k-invariant: hoist (incl. slot->token indirection)
  size_t aoff[4]; size_t boff[4];
#pragma unroll
  for (int i = 0; i < 4; ++i) {
    int s = i * 256 + wave * 64 + lane;
    int row = s >> 3, c2 = s & 7;
    int am = m0 + row;
    size_t arow = (EPI == 0) ? (size_t)s2t[am] : (size_t)am;
    aoff[i] = arow * K + c2 * 8;
    boff[i] = (size_t)(n0 + row) * K + c2 * 8;
  }
  for (int k0 = 0; k0 < K; k0 += 64) {
    __syncthreads();
#pragma unroll
    for (int i = 0; i < 4; ++i) {
      int loff = (i * 256 + wave * 64) * 16;
      load16_lds(A + aoff[i] + k0, (char*)sA + loff);
      load16_lds(Bt + boff[i] + k0, (char*)sB + loff);
    }
    __syncthreads();
#pragma unroll
    for (int ks = 0; ks < 2; ++ks) {
      f16x8 bf[4];
#pragma unroll
      for (int t = 0; t < 4; ++t)
        bf[t] = *(const f16x8*)&sB[(wn * 64 + t * 16 + r16) * 64 + ks * 32 + q * 8];
#pragma unroll
      for (int mt = 0; mt < 4; ++mt) {
        f16x8 af = *(const f16x8*)&sA[(wm * 64 + mt * 16 + r16) * 64 + ks * 32 + q * 8];
#pragma unroll
        for (int nt = 0; nt < 4; ++nt)
          acc[mt][nt] = __builtin_amdgcn_mfma_f32_16x16x32_f16(af, bf[nt], acc[mt][nt], 0, 0, 0);
      }
    }
  }
#pragma unroll
  for (int mt = 0; mt < 4; ++mt)
#pragma unroll
    for (int nt = 0; nt < 4; ++nt) {
      int col = n0 + wn * 64 + nt * 16 + r16;
      float bv = bias_e[col];
#pragma unroll
      for (int r = 0; r < 4; ++r) {
        size_t grow = (size_t)(m0 + wm * 64 + mt * 16 + q * 4 + r);
        float v = acc[mt][nt][r] + bv;
        if (EPI == 0)
          ((_Float16*)out)[grow * N + col] = (_Float16)gelu_f(v);
        else
          ((float*)out)[grow * N + col] = v;
      }
    }
}

// ---------------- combine + final LN ----------------
__global__ void combine_ln_kernel(const float* __restrict__ ybuf, const int* __restrict__ slotmap,
                                  const float* __restrict__ twt, const float* __restrict__ g,
                                  const float* __restrict__ b, float* __restrict__ out) {
  int t = blockIdx.x, tid = threadIdx.x;
  int s0 = slotmap[2 * t], s1 = slotmap[2 * t + 1];
  float w0 = twt[2 * t], w1 = twt[2 * t + 1];
  float4 a = ((const float4*)(ybuf + (size_t)s0 * HD))[tid];
  float4 c = ((const float4*)(ybuf + (size_t)s1 * HD))[tid];
  float4 v;
  v.x = w0 * a.x + w1 * c.x; v.y = w0 * a.y + w1 * c.y;
  v.z = w0 * a.z + w1 * c.z; v.w = w0 * a.w + w1 * c.w;
  float s = v.x + v.y + v.z + v.w;
  float s2 = v.x * v.x + v.y * v.y + v.z * v.z + v.w * v.w;
  __shared__ float red[8];
#pragma unroll
  for (int o = 32; o > 0; o >>= 1) { s += __shfl_xor(s, o, 64); s2 += __shfl_xor(s2, o, 64); }
  if ((tid & 63) == 0) { red[tid >> 6] = s; red[(tid >> 6) + 4] = s2; }
  __syncthreads();
  s = red[0] + red[1] + red[2] + red[3];
  s2 = red[4] + red[5] + red[6] + red[7];
  float mu = s * (1.0f / HD);
  float rstd = 1.0f / sqrtf(s2 * (1.0f / HD) - mu * mu + 1e-5f);
  float4 gv = ((const float4*)g)[tid], bv = ((const float4*)b)[tid];
  float4 o4;
  o4.x = (v.x - mu) * rstd * gv.x + bv.x;
  o4.y = (v.y - mu) * rstd * gv.y + bv.y;
  o4.z = (v.z - mu) * rstd * gv.z + bv.z;
  o4.w = (v.w - mu) * rstd * gv.w + bv.w;
  ((float4*)(out + (size_t)t * HD))[tid] = o4;
}

// ---------------- launch ----------------
extern "C" void kernel_launch(void* const* d_in, const int* in_sizes, int n_in,
                              void* d_out, int out_size, void* d_ws, size_t ws_size,
                              hipStream_t stream) {
  const float* x    = (const float*)d_in[0];
  const float* ln1g = (const float*)d_in[1];
  const float* ln1b = (const float*)d_in[2];
  const float* ln2g = (const float*)d_in[3];
  const float* ln2b = (const float*)d_in[4];
  const float* w1   = (const float*)d_in[5];
  const float* b1   = (const float*)d_in[6];
  const float* w2   = (const float*)d_in[7];
  const float* b2   = (const float*)d_in[8];
  const float* rw   = (const float*)d_in[9];
  const float* ew1  = (const float*)d_in[10];
  const float* eb1  = (const float*)d_in[11];
  const float* ew2  = (const float*)d_in[12];
  const float* eb2  = (const float*)d_in[13];
  const float* lnfg = (const float*)d_in[14];
  const float* lnfb = (const float*)d_in[15];

  char* ws = (char*)d_ws;
  _Float16* acth = (_Float16*)(ws + 0);
  _Float16* actl = (_Float16*)(ws + 33554432);
  _Float16* ew2t = (_Float16*)(ws + 0);
  _Float16* ew1t = (_Float16*)(ws + 33554432);
  _Float16* w1th = (_Float16*)(ws + 67108864);
  _Float16* w1tl = (_Float16*)(ws + 75497472);
  _Float16* x2h  = (_Float16*)(ws + 67108864);
  _Float16* w2th = (_Float16*)(ws + 83886080);
  _Float16* w2tl = (_Float16*)(ws + 92274688);
  _Float16* h1h  = (_Float16*)(ws + 100663296);
  _Float16* h1l  = (_Float16*)(ws + 109051904);
  float*    part = (float*)(ws + 100663296);   // 4 x [4096,1024] f32 = 64 MB
  float*    ybuf = (float*)(ws + 100663296);   // [MAXSLOT,1024] f32 (after reduce)
  _Float16* a1   = (_Float16*)(ws + 167772160);
  const size_t offS = 205520896;
  int*   counts     = (int*)(ws + offS);
  int*   poff       = (int*)(ws + offS + 64);
  int*   tidx       = (int*)(ws + offS + 1024);
  float* twt        = (float*)(ws + offS + 1024 + 32768);
  int*   slotmap    = (int*)(ws + offS + 1024 + 65536);
  int*   slot2token = (int*)(ws + offS + 1024 + 98304);

  float* out  = (float*)d_out;
  float* auxp = out + (size_t)NTOK * HD;

  dim3 b256(256);
  hipMemsetAsync(ws + offS, 0, 64, stream);

  // resmlp weight conversion (expert transposes deferred: dst overlays act)
  transpose_split2<<<dim3(128, 32, 2), b256, 0, stream>>>(w1, w2, w1th, w1tl, w2th, w2tl);

  // resmlp
  ln1_kernel<<<NTOK, b256, 0, stream>>>(x, ln1g, ln1b, h1h, h1l);
  gemm_split_gelu<<<dim3(MLPH / 128, NTOK / 128, 1), b256, 0, stream>>>(
      h1h, h1l, w1th, w1tl, b1, acth, actl, MLPH, HD);
  gemm_split_pk<<<dim3(HD / 128, NTOK / 128, KSPLIT), b256, 0, stream>>>(
      acth, actl, w2th, w2tl, part, HD, MLPH);
  reduce_ln2_router_kernel<<<NTOK, b256, 0, stream>>>(
      part, x, b2, ln2g, ln2b, rw, x2h, tidx, twt, counts);

  // expert weight transposes (act region now dead)
  transpose_f16_2<<<dim3(64, 32, 16), b256, 0, stream>>>(ew1, ew2, ew1t, ew2t);

  // routing tail (single block): offsets + aux + scatter + slot->token
  route_block<<<1, b256, 0, stream>>>(counts, tidx, poff, auxp, slotmap, slot2token);

  // experts (padded buckets, early-exit grid); eg1 gathers A from x2h via s2t
  gemm_expert<0><<<dim3(EXPH / 128, NTOK / 128, NEXP), b256, 0, stream>>>(
      x2h, ew1t, eb1, a1, EXPH, HD, poff, (size_t)EXPH * HD, EXPH, slot2token);
  gemm_expert<1><<<dim3(HD / 128, NTOK / 128, NEXP), b256, 0, stream>>>(
      a1, ew2t, eb2, ybuf, HD, EXPH, poff, (size_t)HD * EXPH, HD, nullptr);

  // combine + final LN
  combine_ln_kernel<<<NTOK, b256, 0, stream>>>(ybuf, slotmap, twt, lnfg, lnfb, out);
}